// Round 17
// baseline (447.759 us; speedup 1.0000x reference)
//
#include <hip/hip_runtime.h>
#include <math.h>

// Problem constants (from reference)
constexpr int N_NODES = 50000;
constexpr int N_EDGES = 1600000;
constexpr int HDIM    = 64;
constexpr int NLAYER  = 5;
constexpr int NBASIS  = 8;
constexpr int TLUT    = 256;           // radial LUT entries (8-bit index)
constexpr float CUT_R = 5.0f;
constexpr float PI_F  = 3.14159265358979f;

// binned scatter: buckets of 256 nodes (r >> 8)
constexpr int NBKT = 196;
constexpr int BCAP = 9216;             // mean 8192 + ~11 sigma
constexpr int TILE = 2048;

typedef __attribute__((ext_vector_type(8))) short short8;   // 8 bf16 (4 VGPRs)
typedef __attribute__((ext_vector_type(4))) float f32x4;    // MFMA acc
#define MFMA16 __builtin_amdgcn_mfma_f32_16x16x32_bf16

__device__ __forceinline__ float siluf(float x) { return x / (1.0f + __expf(-x)); }

// round-to-nearest-even f32 -> bf16 bits
__device__ __forceinline__ unsigned int f2bf(float x) {
    unsigned int b = __float_as_uint(x);
    return (b + 0x7fffu + ((b >> 16) & 1u)) >> 16;
}
__device__ __forceinline__ float bf_lo(unsigned int u) { return __uint_as_float(u << 16); }
__device__ __forceinline__ float bf_hi(unsigned int u) { return __uint_as_float(u & 0xffff0000u); }

// ---------------- setup kernels ----------------

__global__ void k_embed(const int* __restrict__ an, const float* __restrict__ embed,
                        float* __restrict__ feats, unsigned short* __restrict__ featsbf) {
    int i = blockIdx.x * blockDim.x + threadIdx.x;           // N*H threads
    if (i >= N_NODES * HDIM) return;
    int node = i >> 6, h = i & 63;
    float v = embed[an[node] * HDIM + h];
    feats[i] = v;
    featsbf[i] = (unsigned short)f2bf(v);
}

// pass A: block-sort TILE-edge tiles by node bucket (r>>8), append runs to binned[]
// rec packs (col<<16) | (nn<<8) | (r&255): 4 bytes total
__global__ __launch_bounds__(256) void k_binA(const int* __restrict__ row,
                                              const int* __restrict__ col,
                                              const float* __restrict__ pos,
                                              int* __restrict__ btail,
                                              unsigned int* __restrict__ binned) {
    __shared__ unsigned int ent[TILE];    // 8 KB
    __shared__ short bb[TILE];            // 4 KB
    __shared__ unsigned int sorted[TILE]; // 8 KB
    __shared__ short sortedB[TILE];       // 4 KB
    __shared__ int cnt[256], cnt2[256], base[256], gbase[256], scn[256];
    const int tid = threadIdx.x;
    const int t0  = blockIdx.x * TILE;
    const int nv  = min(TILE, N_EDGES - t0);

    cnt[tid] = 0;
    __syncthreads();

    #pragma unroll
    for (int i = 0; i < TILE / 256; ++i) {
        int idx = i * 256 + tid;
        if (idx < nv) {
            int e = t0 + idx;
            int r = row[e], c = col[e];
            float dx = pos[c * 3 + 0] - pos[r * 3 + 0];
            float dy = pos[c * 3 + 1] - pos[r * 3 + 1];
            float dz = pos[c * 3 + 2] - pos[r * 3 + 2];
            float len = sqrtf(dx * dx + dy * dy + dz * dz);
            float t = len * ((float)(TLUT - 1) / CUT_R);
            t = fminf(t, (float)(TLUT - 1));
            unsigned int nn = (unsigned int)(t + 0.5f);
            if (nn > TLUT - 1) nn = TLUT - 1;
            ent[idx] = ((unsigned int)c << 16) | (nn << 8) | ((unsigned int)r & 255u);
            int b = r >> 8;
            bb[idx] = (short)b;
            atomicAdd(&cnt[b], 1);
        }
    }
    __syncthreads();
    int cv = cnt[tid];
    scn[tid] = cv;
    __syncthreads();
    for (int off = 1; off < 256; off <<= 1) {
        int add = (tid >= off) ? scn[tid - off] : 0;
        __syncthreads();
        scn[tid] += add;
        __syncthreads();
    }
    base[tid] = scn[tid] - cv;
    if (tid < NBKT && cv > 0) gbase[tid] = atomicAdd(&btail[tid], cv);
    cnt2[tid] = base[tid];
    __syncthreads();
    #pragma unroll
    for (int i = 0; i < TILE / 256; ++i) {
        int idx = i * 256 + tid;
        if (idx < nv) {
            int b = bb[idx];
            int p = atomicAdd(&cnt2[b], 1);
            sorted[p]  = ent[idx];
            sortedB[p] = (short)b;
        }
    }
    __syncthreads();
    for (int s = tid; s < nv; s += 256) {
        int b = sortedB[s];
        binned[(size_t)b * BCAP + gbase[b] + (s - base[b])] = sorted[s];
    }
}

// exclusive scan of 196 bucket totals (1 block, 256 threads)
__global__ void k_scanB(const int* __restrict__ btail, int* __restrict__ bbase) {
    __shared__ int s[256];
    int t = threadIdx.x;
    int v = (t < NBKT) ? btail[t] : 0;
    s[t] = v; __syncthreads();
    for (int off = 1; off < 256; off <<= 1) {
        int add = (t >= off) ? s[t - off] : 0;
        __syncthreads();
        s[t] += add;
        __syncthreads();
    }
    if (t < NBKT) bbase[t] = s[t] - v;
}

// pass B: one block per 256-node bucket. LDS histogram -> scan -> starts ->
// scatter erec via LDS cursors. No global atomics.
__global__ __launch_bounds__(256) void k_binB(const unsigned int* __restrict__ binned,
                                              const int* __restrict__ btail,
                                              const int* __restrict__ bbase,
                                              int* __restrict__ starts,
                                              unsigned int* __restrict__ erec) {
    __shared__ int hist[256];
    __shared__ int scn[256];
    __shared__ int cur[256];
    const int b = blockIdx.x;
    const int node0 = b << 8;
    const int t = threadIdx.x;
    hist[t] = 0;
    __syncthreads();
    const int cnt = btail[b];
    const unsigned int* src = binned + (size_t)b * BCAP;
    for (int s = t; s < cnt; s += 256)
        atomicAdd(&hist[src[s] & 255u], 1);
    __syncthreads();
    int h = hist[t];
    scn[t] = h;
    __syncthreads();
    for (int off = 1; off < 256; off <<= 1) {
        int add = (t >= off) ? scn[t - off] : 0;
        __syncthreads();
        scn[t] += add;
        __syncthreads();
    }
    int excl = bbase[b] + scn[t] - h;
    int n = node0 + t;
    if (n < N_NODES) starts[n] = excl;
    if (b == 0 && t == 0) starts[N_NODES] = N_EDGES;
    cur[t] = excl;
    __syncthreads();
    for (int s = t; s < cnt; s += 256) {
        unsigned int p = src[s];
        int pp = atomicAdd(&cur[p & 255u], 1);
        erec[pp] = p;
    }
}

// W2s[l][k][h] = sum_{m<3} rad_w2[l][k][h*3+m]; Wsp[l][k][h] = (self_w @ proj_top)[k][h]
__global__ void k_prep(const float* __restrict__ rad_w2, const float* __restrict__ self_w,
                       const float* __restrict__ proj_w,
                       float* __restrict__ W2s, float* __restrict__ Wsp) {
    int i = blockIdx.x * blockDim.x + threadIdx.x;          // L*H*H
    if (i >= NLAYER * HDIM * HDIM) return;
    int l = i / (HDIM * HDIM); int rem = i % (HDIM * HDIM);
    int k = rem / HDIM; int h = rem % HDIM;
    const float* w = rad_w2 + ((size_t)l * HDIM + k) * (HDIM * 3) + h * 3;
    W2s[i] = w[0] + w[1] + w[2];
    const float* sw = self_w + ((size_t)l * HDIM + k) * HDIM;
    const float* pw = proj_w + (size_t)l * 2 * HDIM * HDIM;
    float acc = 0.f;
    for (int m = 0; m < HDIM; ++m) acc += sw[m] * pw[m * HDIM + h];
    Wsp[i] = acc;
}

// bf16 transposed weights for MFMA B-operands: layout [n][k] contiguous in k
__global__ void k_wtr(const float* __restrict__ Wsp, const float* __restrict__ proj_w,
                      const float* __restrict__ mlp_w1, const float* __restrict__ mlp_w2,
                      unsigned short* __restrict__ WspT, unsigned short* __restrict__ PbT,
                      unsigned short* __restrict__ W1T, unsigned short* __restrict__ W2T) {
    int i = blockIdx.x * blockDim.x + threadIdx.x;          // L * 24576
    if (i >= NLAYER * 24576) return;
    int l = i / 24576, off = i % 24576;
    if (off < 4096) {
        int n = off >> 6, k = off & 63;
        WspT[(size_t)l * 4096 + off] = (unsigned short)f2bf(Wsp[(size_t)l * 4096 + k * 64 + n]);
    } else if (off < 8192) {
        int o = off - 4096; int n = o >> 6, k = o & 63;
        PbT[(size_t)l * 4096 + o] =
            (unsigned short)f2bf(proj_w[(size_t)l * 8192 + (64 + k) * 64 + n]);
    } else if (off < 16384) {
        int o = off - 8192; int n = o >> 6, k = o & 63;
        W1T[(size_t)l * 8192 + o] = (unsigned short)f2bf(mlp_w1[(size_t)l * 8192 + k * 128 + n]);
    } else {
        int o = off - 16384; int n = o >> 7, k = o & 127;
        W2T[(size_t)l * 8192 + o] = (unsigned short)f2bf(mlp_w2[(size_t)l * 8192 + k * 64 + n]);
    }
}

// bf16 transposed readout weights: Ro1T[64][64], Ro2T[32][64]
__global__ void k_rotr(const float* __restrict__ ro_w1, const float* __restrict__ ro_w2,
                       unsigned short* __restrict__ Ro1T, unsigned short* __restrict__ Ro2T) {
    int i = blockIdx.x * blockDim.x + threadIdx.x;          // 6144
    if (i >= 6144) return;
    if (i < 4096) {
        int n = i >> 6, k = i & 63;
        Ro1T[i] = (unsigned short)f2bf(ro_w1[k * 64 + n]);
    } else {
        int o = i - 4096; int n = o >> 6, k = o & 63;       // n in 0..31
        Ro2T[o] = (unsigned short)f2bf(ro_w2[k * 32 + n]);
    }
}

// b2s[l][h] = sum_m rad_b2[l][h*3+m];  bsp[l][h] = self_b@proj_top + proj_b
__global__ void k_bias(const float* __restrict__ rad_b2, const float* __restrict__ self_b,
                       const float* __restrict__ proj_w, const float* __restrict__ proj_b,
                       float* __restrict__ b2s, float* __restrict__ bsp) {
    int i = blockIdx.x * blockDim.x + threadIdx.x;          // L*H
    if (i >= NLAYER * HDIM) return;
    int l = i / HDIM, h = i % HDIM;
    const float* rb2 = rad_b2 + l * HDIM * 3 + h * 3;
    b2s[i] = rb2[0] + rb2[1] + rb2[2];
    float acc = proj_b[l * HDIM + h];
    const float* pw = proj_w + (size_t)l * 2 * HDIM * HDIM;
    const float* sb = self_b + l * HDIM;
    for (int m = 0; m < HDIM; ++m) acc += sb[m] * pw[m * HDIM + h];
    bsp[i] = acc;
}

// radial LUT
__global__ void k_lut(const float* __restrict__ widths, const float* __restrict__ rad_w1,
                      const float* __restrict__ rad_b1, const float* __restrict__ W2s,
                      const float* __restrict__ b2s, float* __restrict__ lut) {
    int bid = blockIdx.x;                 // l*TLUT + t
    int l = bid / TLUT, t = bid % TLUT;
    int h = threadIdx.x;                  // 64 threads
    __shared__ float h1s[HDIM];
    float len = (float)t * (CUT_R / (float)(TLUT - 1));
    float cut = 0.0f;
    if (len < CUT_R) cut = 0.5f * (cosf(len * (PI_F / CUT_R)) + 1.0f);
    float acc = rad_b1[l * HDIM + h];
    for (int b = 0; b < NBASIS; ++b) {
        float wb = fmaxf(widths[b], 0.1f);
        float center = (float)b * (CUT_R / (float)(NBASIS - 1));
        float d = (len - center) / wb;
        float rbf = __expf(-0.5f * d * d) * cut;
        acc += rbf * rad_w1[(l * NBASIS + b) * HDIM + h];
    }
    h1s[h] = siluf(acc);
    __syncthreads();
    float o = b2s[l * HDIM + h];
    const float* w2 = W2s + (size_t)l * HDIM * HDIM;
    for (int k = 0; k < HDIM; ++k) o += h1s[k] * w2[k * HDIM + h];
    lut[(size_t)bid * HDIM + h] = o;
}

// bf16 LUT rows for nearest-neighbor lookup: lutB[l][t][64]
__global__ void k_lutb(const float* __restrict__ lut, unsigned short* __restrict__ lutB) {
    int i = blockIdx.x * blockDim.x + threadIdx.x;          // L*TLUT*64
    if (i >= NLAYER * TLUT * HDIM) return;
    lutB[i] = (unsigned short)f2bf(lut[i]);
}

// ---------------- per-layer kernels ----------------

// one wave per node, 16 edge slots x 4 lanes (16 channels each via 2x uint4).
__global__ __launch_bounds__(256) void k_agg(const uint4* __restrict__ featsbf4,
                                             const uint4* __restrict__ lutB4_l,
                                             const int* __restrict__ starts,
                                             const unsigned int* __restrict__ erec,
                                             uint4* __restrict__ aggbf4) {
    int wid  = (blockIdx.x * blockDim.x + threadIdx.x) >> 6;
    int lane = threadIdx.x & 63;
    int slot = lane >> 2;     // 0..15
    int j    = lane & 3;      // owns channel range [16j, 16j+16)
    if (wid >= N_NODES) return;
    int e0 = starts[wid], e1 = starts[wid + 1];
    float a[16];
    #pragma unroll
    for (int q = 0; q < 16; ++q) a[q] = 0.f;
    #pragma unroll 1
    for (int e = e0 + slot; e < e1; e += 16) {
        unsigned int rec = erec[e];
        int c  = rec >> 16;
        int i0 = (rec >> 8) & 255;
        uint4 q0 = lutB4_l[i0 * 8 + 2 * j];
        uint4 q1 = lutB4_l[i0 * 8 + 2 * j + 1];
        uint4 f0 = featsbf4[(size_t)c * 8 + 2 * j];
        uint4 f1 = featsbf4[(size_t)c * 8 + 2 * j + 1];
        a[0]  += bf_lo(f0.x) * bf_lo(q0.x);  a[1]  += bf_hi(f0.x) * bf_hi(q0.x);
        a[2]  += bf_lo(f0.y) * bf_lo(q0.y);  a[3]  += bf_hi(f0.y) * bf_hi(q0.y);
        a[4]  += bf_lo(f0.z) * bf_lo(q0.z);  a[5]  += bf_hi(f0.z) * bf_hi(q0.z);
        a[6]  += bf_lo(f0.w) * bf_lo(q0.w);  a[7]  += bf_hi(f0.w) * bf_hi(q0.w);
        a[8]  += bf_lo(f1.x) * bf_lo(q1.x);  a[9]  += bf_hi(f1.x) * bf_hi(q1.x);
        a[10] += bf_lo(f1.y) * bf_lo(q1.y);  a[11] += bf_hi(f1.y) * bf_hi(q1.y);
        a[12] += bf_lo(f1.z) * bf_lo(q1.z);  a[13] += bf_hi(f1.z) * bf_hi(q1.z);
        a[14] += bf_lo(f1.w) * bf_lo(q1.w);  a[15] += bf_hi(f1.w) * bf_hi(q1.w);
    }
    #pragma unroll
    for (int off = 4; off < 64; off <<= 1) {
        #pragma unroll
        for (int q = 0; q < 16; ++q) a[q] += __shfl_xor(a[q], off, 64);
    }
    if (slot == 0) {
        uint4 o0, o1;
        o0.x = f2bf(a[0])  | (f2bf(a[1])  << 16);
        o0.y = f2bf(a[2])  | (f2bf(a[3])  << 16);
        o0.z = f2bf(a[4])  | (f2bf(a[5])  << 16);
        o0.w = f2bf(a[6])  | (f2bf(a[7])  << 16);
        o1.x = f2bf(a[8])  | (f2bf(a[9])  << 16);
        o1.y = f2bf(a[10]) | (f2bf(a[11]) << 16);
        o1.z = f2bf(a[12]) | (f2bf(a[13]) << 16);
        o1.w = f2bf(a[14]) | (f2bf(a[15]) << 16);
        aggbf4[(size_t)wid * 8 + 2 * j]     = o0;
        aggbf4[(size_t)wid * 8 + 2 * j + 1] = o1;
    }
}

// k_node v3 (MFMA): 64 nodes/block, 4 waves; wave w owns node rows [16w,16w+16).
constexpr int BP = 72;                     // bf16 LDS row pitch
__global__ __launch_bounds__(256) void k_node(float* __restrict__ feats,
        unsigned short* __restrict__ featsbf,
        const unsigned short* __restrict__ aggbf,
        const unsigned short* __restrict__ WspT_l, const unsigned short* __restrict__ PbT_l,
        const unsigned short* __restrict__ W1T_l, const unsigned short* __restrict__ W2T_l,
        const float* __restrict__ bsp_l,
        const float* __restrict__ mlp_b1_l, const float* __restrict__ mlp_b2_l,
        const float* __restrict__ ln_g_l, const float* __restrict__ ln_b_l) {
    __shared__ unsigned short P[64 * BP];   // x -> conv
    __shared__ unsigned short Q[64 * BP];   // a -> m1_lo
    __shared__ unsigned short S[64 * BP];   // m1_hi
    const int tid  = threadIdx.x;
    const int lane = tid & 63;
    const int wib  = tid >> 6;
    const int mt   = __builtin_amdgcn_readfirstlane(wib);
    const int nb0  = blockIdx.x * 64;
    const int colL = lane & 15;
    const int kgrp = lane >> 4;

    #pragma unroll 4
    for (int i = 0; i < 16; ++i) {
        int r  = wib + i * 4;
        int nd = nb0 + r; nd = (nd < N_NODES) ? nd : (N_NODES - 1);
        P[r * BP + lane] = featsbf[(size_t)nd * 64 + lane];
        Q[r * BP + lane] = aggbf[(size_t)nd * 64 + lane];
    }
    __syncthreads();

    // ---- conv = x@Wsp + a@Pb + bsp ----
    f32x4 acc[4];
    #pragma unroll
    for (int nt = 0; nt < 4; ++nt) {
        float b = bsp_l[nt * 16 + colL];
        acc[nt][0] = b; acc[nt][1] = b; acc[nt][2] = b; acc[nt][3] = b;
    }
    #pragma unroll
    for (int kb = 0; kb < 2; ++kb) {
        short8 ax = *(const short8*)&P[(mt * 16 + colL) * BP + kb * 32 + kgrp * 8];
        short8 aa = *(const short8*)&Q[(mt * 16 + colL) * BP + kb * 32 + kgrp * 8];
        #pragma unroll
        for (int nt = 0; nt < 4; ++nt) {
            short8 bw = *(const short8*)&WspT_l[(nt * 16 + colL) * 64 + kb * 32 + kgrp * 8];
            acc[nt] = MFMA16(ax, bw, acc[nt], 0, 0, 0);
            short8 bp = *(const short8*)&PbT_l[(nt * 16 + colL) * 64 + kb * 32 + kgrp * 8];
            acc[nt] = MFMA16(aa, bp, acc[nt], 0, 0, 0);
        }
    }
    __syncthreads();
    #pragma unroll
    for (int nt = 0; nt < 4; ++nt)
        #pragma unroll
        for (int j = 0; j < 4; ++j)
            P[(mt * 16 + kgrp * 4 + j) * BP + nt * 16 + colL] = (unsigned short)f2bf(acc[nt][j]);
    __syncthreads();

    // ---- m1 = silu(conv@W1 + b1), 128 wide ----
    {
        f32x4 m[8];
        #pragma unroll
        for (int nt = 0; nt < 8; ++nt) {
            float b = mlp_b1_l[nt * 16 + colL];
            m[nt][0] = b; m[nt][1] = b; m[nt][2] = b; m[nt][3] = b;
        }
        #pragma unroll
        for (int kb = 0; kb < 2; ++kb) {
            short8 ac = *(const short8*)&P[(mt * 16 + colL) * BP + kb * 32 + kgrp * 8];
            #pragma unroll
            for (int nt = 0; nt < 8; ++nt) {
                short8 bw = *(const short8*)&W1T_l[(nt * 16 + colL) * 64 + kb * 32 + kgrp * 8];
                m[nt] = MFMA16(ac, bw, m[nt], 0, 0, 0);
            }
        }
        __syncthreads();
        #pragma unroll
        for (int nt = 0; nt < 4; ++nt)
            #pragma unroll
            for (int j = 0; j < 4; ++j)
                Q[(mt * 16 + kgrp * 4 + j) * BP + nt * 16 + colL] =
                    (unsigned short)f2bf(siluf(m[nt][j]));
        #pragma unroll
        for (int nt = 4; nt < 8; ++nt)
            #pragma unroll
            for (int j = 0; j < 4; ++j)
                S[(mt * 16 + kgrp * 4 + j) * BP + (nt - 4) * 16 + colL] =
                    (unsigned short)f2bf(siluf(m[nt][j]));
    }
    __syncthreads();

    // ---- upd = m1@W2 + b2 ----
    f32x4 u[4];
    #pragma unroll
    for (int nt = 0; nt < 4; ++nt) {
        float b = mlp_b2_l[nt * 16 + colL];
        u[nt][0] = b; u[nt][1] = b; u[nt][2] = b; u[nt][3] = b;
    }
    #pragma unroll
    for (int kb = 0; kb < 4; ++kb) {
        short8 am = (kb < 2)
            ? *(const short8*)&Q[(mt * 16 + colL) * BP + kb * 32 + kgrp * 8]
            : *(const short8*)&S[(mt * 16 + colL) * BP + (kb - 2) * 32 + kgrp * 8];
        #pragma unroll
        for (int nt = 0; nt < 4; ++nt) {
            short8 bw = *(const short8*)&W2T_l[(nt * 16 + colL) * 128 + kb * 32 + kgrp * 8];
            u[nt] = MFMA16(am, bw, u[nt], 0, 0, 0);
        }
    }

    // ---- residual + LayerNorm ----
    float y[4][4];
    float s1[4] = {0, 0, 0, 0}, s2[4] = {0, 0, 0, 0};
    #pragma unroll
    for (int j = 0; j < 4; ++j) {
        int node = nb0 + mt * 16 + kgrp * 4 + j;
        int nds  = (node < N_NODES) ? node : (N_NODES - 1);
        #pragma unroll
        for (int nt = 0; nt < 4; ++nt) {
            float v = feats[(size_t)nds * 64 + nt * 16 + colL] + u[nt][j];
            y[nt][j] = v;
            s1[j] += v; s2[j] += v * v;
        }
    }
    #pragma unroll
    for (int off = 1; off < 16; off <<= 1) {
        #pragma unroll
        for (int j = 0; j < 4; ++j) {
            s1[j] += __shfl_xor(s1[j], off, 64);
            s2[j] += __shfl_xor(s2[j], off, 64);
        }
    }
    float gv[4], bv[4];
    #pragma unroll
    for (int nt = 0; nt < 4; ++nt) {
        gv[nt] = ln_g_l[nt * 16 + colL];
        bv[nt] = ln_b_l[nt * 16 + colL];
    }
    #pragma unroll
    for (int j = 0; j < 4; ++j) {
        int node = nb0 + mt * 16 + kgrp * 4 + j;
        if (node >= N_NODES) continue;
        float mu  = s1[j] * (1.0f / 64.0f);
        float var = s2[j] * (1.0f / 64.0f) - mu * mu;
        float rr  = rsqrtf(var + 1e-5f);
        #pragma unroll
        for (int nt = 0; nt < 4; ++nt) {
            float o = (y[nt][j] - mu) * rr * gv[nt] + bv[nt];
            feats[(size_t)node * 64 + nt * 16 + colL]   = o;
            featsbf[(size_t)node * 64 + nt * 16 + colL] = (unsigned short)f2bf(o);
        }
    }
}

// ---------------- readout (MFMA, k_node template) ----------------

__global__ __launch_bounds__(256) void k_readout(const unsigned short* __restrict__ featsbf,
        const int* __restrict__ an,
        const unsigned short* __restrict__ Ro1T, const unsigned short* __restrict__ Ro2T,
        const float* __restrict__ ro_b1, const float* __restrict__ ro_b2,
        const float* __restrict__ ro_w3, const float* __restrict__ ro_b3,
        const float* __restrict__ atomic_e, float* __restrict__ blockpart) {
    __shared__ unsigned short P[64 * BP];   // feats
    __shared__ unsigned short Q[64 * BP];   // h1
    __shared__ float sred[256];
    const int tid  = threadIdx.x;
    const int lane = tid & 63;
    const int wib  = tid >> 6;
    const int mt   = __builtin_amdgcn_readfirstlane(wib);
    const int nb0  = blockIdx.x * 64;
    const int colL = lane & 15;
    const int kgrp = lane >> 4;

    #pragma unroll 4
    for (int i = 0; i < 16; ++i) {
        int r  = wib + i * 4;
        int nd = nb0 + r; nd = (nd < N_NODES) ? nd : (N_NODES - 1);
        P[r * BP + lane] = featsbf[(size_t)nd * 64 + lane];
    }
    __syncthreads();

    // ---- h1 = silu(x @ Ro1 + b1) ----
    {
        f32x4 m[4];
        #pragma unroll
        for (int nt = 0; nt < 4; ++nt) {
            float b = ro_b1[nt * 16 + colL];
            m[nt][0] = b; m[nt][1] = b; m[nt][2] = b; m[nt][3] = b;
        }
        #pragma unroll
        for (int kb = 0; kb < 2; ++kb) {
            short8 ax = *(const short8*)&P[(mt * 16 + colL) * BP + kb * 32 + kgrp * 8];
            #pragma unroll
            for (int nt = 0; nt < 4; ++nt) {
                short8 bw = *(const short8*)&Ro1T[(nt * 16 + colL) * 64 + kb * 32 + kgrp * 8];
                m[nt] = MFMA16(ax, bw, m[nt], 0, 0, 0);
            }
        }
        __syncthreads();
        #pragma unroll
        for (int nt = 0; nt < 4; ++nt)
            #pragma unroll
            for (int j = 0; j < 4; ++j)
                Q[(mt * 16 + kgrp * 4 + j) * BP + nt * 16 + colL] =
                    (unsigned short)f2bf(siluf(m[nt][j]));
    }
    __syncthreads();

    // ---- h2 = silu(h1 @ Ro2 + b2), 32 wide; e = h2 @ ro_w3 ----
    f32x4 u[2];
    #pragma unroll
    for (int nt = 0; nt < 2; ++nt) {
        float b = ro_b2[nt * 16 + colL];
        u[nt][0] = b; u[nt][1] = b; u[nt][2] = b; u[nt][3] = b;
    }
    #pragma unroll
    for (int kb = 0; kb < 2; ++kb) {
        short8 am = *(const short8*)&Q[(mt * 16 + colL) * BP + kb * 32 + kgrp * 8];
        #pragma unroll
        for (int nt = 0; nt < 2; ++nt) {
            short8 bw = *(const short8*)&Ro2T[(nt * 16 + colL) * 64 + kb * 32 + kgrp * 8];
            u[nt] = MFMA16(am, bw, u[nt], 0, 0, 0);
        }
    }
    float w3[2];
    #pragma unroll
    for (int nt = 0; nt < 2; ++nt) w3[nt] = ro_w3[nt * 16 + colL];
    float part = 0.0f;
    #pragma unroll
    for (int j = 0; j < 4; ++j) {
        float c = siluf(u[0][j]) * w3[0] + siluf(u[1][j]) * w3[1];
        #pragma unroll
        for (int off = 1; off < 16; off <<= 1) c += __shfl_xor(c, off, 64);
        int node = nb0 + mt * 16 + kgrp * 4 + j;
        if (colL == 0 && node < N_NODES)
            part += c + ro_b3[0] + atomic_e[an[node]];
    }
    sred[tid] = part;
    __syncthreads();
    for (int off = 128; off > 0; off >>= 1) {
        if (tid < off) sred[tid] += sred[tid + off];
        __syncthreads();
    }
    if (tid == 0) blockpart[blockIdx.x] = sred[0];
}

__global__ void k_final(const float* __restrict__ blockpart, int nb, float* __restrict__ out) {
    __shared__ float s[256];
    float acc = 0.f;
    for (int i = threadIdx.x; i < nb; i += 256) acc += blockpart[i];
    s[threadIdx.x] = acc; __syncthreads();
    for (int off = 128; off > 0; off >>= 1) {
        if (threadIdx.x < off) s[threadIdx.x] += s[threadIdx.x + off];
        __syncthreads();
    }
    if (threadIdx.x == 0) out[0] = s[0];
}

// ---------------- launch ----------------

extern "C" void kernel_launch(void* const* d_in, const int* in_sizes, int n_in,
                              void* d_out, int out_size, void* d_ws, size_t ws_size,
                              hipStream_t stream) {
    const int*   an       = (const int*)  d_in[0];
    const float* pos      = (const float*)d_in[1];
    const int*   edge     = (const int*)  d_in[2];
    const float* widths   = (const float*)d_in[3];
    const float* embed    = (const float*)d_in[4];
    const float* rad_w1   = (const float*)d_in[5];
    const float* rad_b1   = (const float*)d_in[6];
    const float* rad_w2   = (const float*)d_in[7];
    const float* rad_b2   = (const float*)d_in[8];
    const float* self_w   = (const float*)d_in[9];
    const float* self_b   = (const float*)d_in[10];
    const float* proj_w   = (const float*)d_in[11];
    const float* proj_b   = (const float*)d_in[12];
    const float* mlp_w1   = (const float*)d_in[13];
    const float* mlp_b1   = (const float*)d_in[14];
    const float* mlp_w2   = (const float*)d_in[15];
    const float* mlp_b2   = (const float*)d_in[16];
    const float* ln_g     = (const float*)d_in[17];
    const float* ln_b     = (const float*)d_in[18];
    const float* ro_w1    = (const float*)d_in[19];
    const float* ro_b1    = (const float*)d_in[20];
    const float* ro_w2    = (const float*)d_in[21];
    const float* ro_b2    = (const float*)d_in[22];
    const float* ro_w3    = (const float*)d_in[23];
    const float* ro_b3    = (const float*)d_in[24];
    const float* atomic_e = (const float*)d_in[25];

    char* w = (char*)d_ws;
    auto alloc = [&](size_t bytes) { char* p = w; w += (bytes + 255) & ~(size_t)255; return p; };
    float* feats     = (float*)alloc(sizeof(float) * N_NODES * HDIM);
    unsigned short* featsbf = (unsigned short*)alloc(sizeof(unsigned short) * N_NODES * HDIM);
    unsigned short* aggbf   = (unsigned short*)alloc(sizeof(unsigned short) * N_NODES * HDIM);
    float* lut       = (float*)alloc(sizeof(float) * NLAYER * TLUT * HDIM);
    unsigned short* lutB = (unsigned short*)alloc(sizeof(unsigned short) * NLAYER * TLUT * HDIM);
    float* W2s       = (float*)alloc(sizeof(float) * NLAYER * HDIM * HDIM);
    float* b2s       = (float*)alloc(sizeof(float) * NLAYER * HDIM);
    float* Wsp       = (float*)alloc(sizeof(float) * NLAYER * HDIM * HDIM);
    float* bsp       = (float*)alloc(sizeof(float) * NLAYER * HDIM);
    unsigned short* WspT = (unsigned short*)alloc(sizeof(unsigned short) * NLAYER * 4096);
    unsigned short* PbT  = (unsigned short*)alloc(sizeof(unsigned short) * NLAYER * 4096);
    unsigned short* W1T  = (unsigned short*)alloc(sizeof(unsigned short) * NLAYER * 8192);
    unsigned short* W2T  = (unsigned short*)alloc(sizeof(unsigned short) * NLAYER * 8192);
    unsigned short* Ro1T = (unsigned short*)alloc(sizeof(unsigned short) * 4096);
    unsigned short* Ro2T = (unsigned short*)alloc(sizeof(unsigned short) * 2048);
    unsigned int* erec = (unsigned int*)alloc(sizeof(unsigned int) * N_EDGES);
    unsigned int* binned = (unsigned int*)alloc(sizeof(unsigned int) * (size_t)NBKT * BCAP);
    int*   btail     = (int*)  alloc(sizeof(int) * 256);
    int*   bbase     = (int*)  alloc(sizeof(int) * 256);
    int*   starts    = (int*)  alloc(sizeof(int) * (N_NODES + 1));
    float* blockpart = (float*)alloc(sizeof(float) * 1024);
    (void)ws_size; (void)in_sizes; (void)n_in; (void)out_size;

    const int* erow = edge;
    const int* ecol = edge + N_EDGES;

    hipMemsetAsync(btail, 0, sizeof(int) * 256, stream);
    k_embed<<<12500, 256, 0, stream>>>(an, embed, feats, featsbf);
    k_binA<<<(N_EDGES + TILE - 1) / TILE, 256, 0, stream>>>(erow, ecol, pos, btail, binned);
    k_scanB<<<1, 256, 0, stream>>>(btail, bbase);
    k_binB<<<NBKT, 256, 0, stream>>>(binned, btail, bbase, starts, erec);
    k_prep<<<80, 256, 0, stream>>>(rad_w2, self_w, proj_w, W2s, Wsp);
    k_wtr<<<(NLAYER * 24576 + 255) / 256, 256, 0, stream>>>(Wsp, proj_w, mlp_w1, mlp_w2,
                                                            WspT, PbT, W1T, W2T);
    k_rotr<<<24, 256, 0, stream>>>(ro_w1, ro_w2, Ro1T, Ro2T);
    k_bias<<<5, 64, 0, stream>>>(rad_b2, self_b, proj_w, proj_b, b2s, bsp);
    k_lut<<<NLAYER * TLUT, 64, 0, stream>>>(widths, rad_w1, rad_b1, W2s, b2s, lut);
    k_lutb<<<(NLAYER * TLUT * HDIM + 255) / 256, 256, 0, stream>>>(lut, lutB);

    for (int l = 0; l < NLAYER; ++l) {
        k_agg<<<12500, 256, 0, stream>>>((const uint4*)featsbf,
                                         (const uint4*)(lutB + (size_t)l * TLUT * HDIM),
                                         starts, erec, (uint4*)aggbf);
        k_node<<<782, 256, 0, stream>>>(feats, featsbf, aggbf,
            WspT + (size_t)l * 4096, PbT + (size_t)l * 4096,
            W1T + (size_t)l * 8192, W2T + (size_t)l * 8192,
            bsp + l * HDIM, mlp_b1 + l * 2 * HDIM, mlp_b2 + l * HDIM,
            ln_g + l * HDIM, ln_b + l * HDIM);
    }

    k_readout<<<782, 256, 0, stream>>>(featsbf, an, Ro1T, Ro2T, ro_b1, ro_b2,
                                       ro_w3, ro_b3, atomic_e, blockpart);
    k_final<<<1, 256, 0, stream>>>(blockpart, 782, (float*)d_out);
}

// Round 18
// 411.774 us; speedup vs baseline: 1.0874x; 1.0874x over previous
//
#include <hip/hip_runtime.h>
#include <math.h>

// Problem constants (from reference)
constexpr int N_NODES = 50000;
constexpr int N_EDGES = 1600000;
constexpr int HDIM    = 64;
constexpr int NLAYER  = 5;
constexpr int NBASIS  = 8;
constexpr int TLUT    = 256;           // radial LUT entries (8-bit index)
constexpr float CUT_R = 5.0f;
constexpr float PI_F  = 3.14159265358979f;

// binned scatter: buckets of 256 nodes (r >> 8)
constexpr int NBKT = 196;
constexpr int BCAP = 9216;             // mean 8192 + ~11 sigma
constexpr int TILE = 2048;

typedef __attribute__((ext_vector_type(8))) short short8;   // 8 bf16 (4 VGPRs)
typedef __attribute__((ext_vector_type(4))) float f32x4;    // MFMA acc
#define MFMA16 __builtin_amdgcn_mfma_f32_16x16x32_bf16

__device__ __forceinline__ float siluf(float x) { return x / (1.0f + __expf(-x)); }

// round-to-nearest-even f32 -> bf16 bits
__device__ __forceinline__ unsigned int f2bf(float x) {
    unsigned int b = __float_as_uint(x);
    return (b + 0x7fffu + ((b >> 16) & 1u)) >> 16;
}
__device__ __forceinline__ float bf_lo(unsigned int u) { return __uint_as_float(u << 16); }
__device__ __forceinline__ float bf_hi(unsigned int u) { return __uint_as_float(u & 0xffff0000u); }

// ---------------- setup kernels ----------------

__global__ void k_embed(const int* __restrict__ an, const float* __restrict__ embed,
                        float* __restrict__ feats, unsigned short* __restrict__ featsbf) {
    int i = blockIdx.x * blockDim.x + threadIdx.x;           // N*H threads
    if (i >= N_NODES * HDIM) return;
    int node = i >> 6, h = i & 63;
    float v = embed[an[node] * HDIM + h];
    feats[i] = v;
    featsbf[i] = (unsigned short)f2bf(v);
}

// pass A: block-sort TILE-edge tiles by node bucket (r>>8), append runs to binned[]
// rec packs (col<<16) | (nn<<8) | (r&255): 4 bytes total
__global__ __launch_bounds__(256) void k_binA(const int* __restrict__ row,
                                              const int* __restrict__ col,
                                              const float* __restrict__ pos,
                                              int* __restrict__ btail,
                                              unsigned int* __restrict__ binned) {
    __shared__ unsigned int ent[TILE];    // 8 KB
    __shared__ short bb[TILE];            // 4 KB
    __shared__ unsigned int sorted[TILE]; // 8 KB
    __shared__ short sortedB[TILE];       // 4 KB
    __shared__ int cnt[256], cnt2[256], base[256], gbase[256], scn[256];
    const int tid = threadIdx.x;
    const int t0  = blockIdx.x * TILE;
    const int nv  = min(TILE, N_EDGES - t0);

    cnt[tid] = 0;
    __syncthreads();

    #pragma unroll
    for (int i = 0; i < TILE / 256; ++i) {
        int idx = i * 256 + tid;
        if (idx < nv) {
            int e = t0 + idx;
            int r = row[e], c = col[e];
            float dx = pos[c * 3 + 0] - pos[r * 3 + 0];
            float dy = pos[c * 3 + 1] - pos[r * 3 + 1];
            float dz = pos[c * 3 + 2] - pos[r * 3 + 2];
            float len = sqrtf(dx * dx + dy * dy + dz * dz);
            float t = len * ((float)(TLUT - 1) / CUT_R);
            t = fminf(t, (float)(TLUT - 1));
            unsigned int nn = (unsigned int)(t + 0.5f);
            if (nn > TLUT - 1) nn = TLUT - 1;
            ent[idx] = ((unsigned int)c << 16) | (nn << 8) | ((unsigned int)r & 255u);
            int b = r >> 8;
            bb[idx] = (short)b;
            atomicAdd(&cnt[b], 1);
        }
    }
    __syncthreads();
    int cv = cnt[tid];
    scn[tid] = cv;
    __syncthreads();
    for (int off = 1; off < 256; off <<= 1) {
        int add = (tid >= off) ? scn[tid - off] : 0;
        __syncthreads();
        scn[tid] += add;
        __syncthreads();
    }
    base[tid] = scn[tid] - cv;
    if (tid < NBKT && cv > 0) gbase[tid] = atomicAdd(&btail[tid], cv);
    cnt2[tid] = base[tid];
    __syncthreads();
    #pragma unroll
    for (int i = 0; i < TILE / 256; ++i) {
        int idx = i * 256 + tid;
        if (idx < nv) {
            int b = bb[idx];
            int p = atomicAdd(&cnt2[b], 1);
            sorted[p]  = ent[idx];
            sortedB[p] = (short)b;
        }
    }
    __syncthreads();
    for (int s = tid; s < nv; s += 256) {
        int b = sortedB[s];
        binned[(size_t)b * BCAP + gbase[b] + (s - base[b])] = sorted[s];
    }
}

// exclusive scan of 196 bucket totals (1 block, 256 threads)
__global__ void k_scanB(const int* __restrict__ btail, int* __restrict__ bbase) {
    __shared__ int s[256];
    int t = threadIdx.x;
    int v = (t < NBKT) ? btail[t] : 0;
    s[t] = v; __syncthreads();
    for (int off = 1; off < 256; off <<= 1) {
        int add = (t >= off) ? s[t - off] : 0;
        __syncthreads();
        s[t] += add;
        __syncthreads();
    }
    if (t < NBKT) bbase[t] = s[t] - v;
}

// pass B: one block per 256-node bucket. LDS histogram -> scan -> starts ->
// scatter erec via LDS cursors. No global atomics.
__global__ __launch_bounds__(256) void k_binB(const unsigned int* __restrict__ binned,
                                              const int* __restrict__ btail,
                                              const int* __restrict__ bbase,
                                              int* __restrict__ starts,
                                              unsigned int* __restrict__ erec) {
    __shared__ int hist[256];
    __shared__ int scn[256];
    __shared__ int cur[256];
    const int b = blockIdx.x;
    const int node0 = b << 8;
    const int t = threadIdx.x;
    hist[t] = 0;
    __syncthreads();
    const int cnt = btail[b];
    const unsigned int* src = binned + (size_t)b * BCAP;
    for (int s = t; s < cnt; s += 256)
        atomicAdd(&hist[src[s] & 255u], 1);
    __syncthreads();
    int h = hist[t];
    scn[t] = h;
    __syncthreads();
    for (int off = 1; off < 256; off <<= 1) {
        int add = (t >= off) ? scn[t - off] : 0;
        __syncthreads();
        scn[t] += add;
        __syncthreads();
    }
    int excl = bbase[b] + scn[t] - h;
    int n = node0 + t;
    if (n < N_NODES) starts[n] = excl;
    if (b == 0 && t == 0) starts[N_NODES] = N_EDGES;
    cur[t] = excl;
    __syncthreads();
    for (int s = t; s < cnt; s += 256) {
        unsigned int p = src[s];
        int pp = atomicAdd(&cur[p & 255u], 1);
        erec[pp] = p;
    }
}

// W2s[l][k][h] = sum_{m<3} rad_w2[l][k][h*3+m]; Wsp[l][k][h] = (self_w @ proj_top)[k][h]
__global__ void k_prep(const float* __restrict__ rad_w2, const float* __restrict__ self_w,
                       const float* __restrict__ proj_w,
                       float* __restrict__ W2s, float* __restrict__ Wsp) {
    int i = blockIdx.x * blockDim.x + threadIdx.x;          // L*H*H
    if (i >= NLAYER * HDIM * HDIM) return;
    int l = i / (HDIM * HDIM); int rem = i % (HDIM * HDIM);
    int k = rem / HDIM; int h = rem % HDIM;
    const float* w = rad_w2 + ((size_t)l * HDIM + k) * (HDIM * 3) + h * 3;
    W2s[i] = w[0] + w[1] + w[2];
    const float* sw = self_w + ((size_t)l * HDIM + k) * HDIM;
    const float* pw = proj_w + (size_t)l * 2 * HDIM * HDIM;
    float acc = 0.f;
    for (int m = 0; m < HDIM; ++m) acc += sw[m] * pw[m * HDIM + h];
    Wsp[i] = acc;
}

// bf16 transposed weights for MFMA B-operands: layout [n][k] contiguous in k
__global__ void k_wtr(const float* __restrict__ Wsp, const float* __restrict__ proj_w,
                      const float* __restrict__ mlp_w1, const float* __restrict__ mlp_w2,
                      unsigned short* __restrict__ WspT, unsigned short* __restrict__ PbT,
                      unsigned short* __restrict__ W1T, unsigned short* __restrict__ W2T) {
    int i = blockIdx.x * blockDim.x + threadIdx.x;          // L * 24576
    if (i >= NLAYER * 24576) return;
    int l = i / 24576, off = i % 24576;
    if (off < 4096) {
        int n = off >> 6, k = off & 63;
        WspT[(size_t)l * 4096 + off] = (unsigned short)f2bf(Wsp[(size_t)l * 4096 + k * 64 + n]);
    } else if (off < 8192) {
        int o = off - 4096; int n = o >> 6, k = o & 63;
        PbT[(size_t)l * 4096 + o] =
            (unsigned short)f2bf(proj_w[(size_t)l * 8192 + (64 + k) * 64 + n]);
    } else if (off < 16384) {
        int o = off - 8192; int n = o >> 6, k = o & 63;
        W1T[(size_t)l * 8192 + o] = (unsigned short)f2bf(mlp_w1[(size_t)l * 8192 + k * 128 + n]);
    } else {
        int o = off - 16384; int n = o >> 7, k = o & 127;
        W2T[(size_t)l * 8192 + o] = (unsigned short)f2bf(mlp_w2[(size_t)l * 8192 + k * 64 + n]);
    }
}

// bf16 transposed readout weights: Ro1T[64][64], Ro2T[32][64]
__global__ void k_rotr(const float* __restrict__ ro_w1, const float* __restrict__ ro_w2,
                       unsigned short* __restrict__ Ro1T, unsigned short* __restrict__ Ro2T) {
    int i = blockIdx.x * blockDim.x + threadIdx.x;          // 6144
    if (i >= 6144) return;
    if (i < 4096) {
        int n = i >> 6, k = i & 63;
        Ro1T[i] = (unsigned short)f2bf(ro_w1[k * 64 + n]);
    } else {
        int o = i - 4096; int n = o >> 6, k = o & 63;       // n in 0..31
        Ro2T[o] = (unsigned short)f2bf(ro_w2[k * 32 + n]);
    }
}

// b2s[l][h] = sum_m rad_b2[l][h*3+m];  bsp[l][h] = self_b@proj_top + proj_b
__global__ void k_bias(const float* __restrict__ rad_b2, const float* __restrict__ self_b,
                       const float* __restrict__ proj_w, const float* __restrict__ proj_b,
                       float* __restrict__ b2s, float* __restrict__ bsp) {
    int i = blockIdx.x * blockDim.x + threadIdx.x;          // L*H
    if (i >= NLAYER * HDIM) return;
    int l = i / HDIM, h = i % HDIM;
    const float* rb2 = rad_b2 + l * HDIM * 3 + h * 3;
    b2s[i] = rb2[0] + rb2[1] + rb2[2];
    float acc = proj_b[l * HDIM + h];
    const float* pw = proj_w + (size_t)l * 2 * HDIM * HDIM;
    const float* sb = self_b + l * HDIM;
    for (int m = 0; m < HDIM; ++m) acc += sb[m] * pw[m * HDIM + h];
    bsp[i] = acc;
}

// radial LUT
__global__ void k_lut(const float* __restrict__ widths, const float* __restrict__ rad_w1,
                      const float* __restrict__ rad_b1, const float* __restrict__ W2s,
                      const float* __restrict__ b2s, float* __restrict__ lut) {
    int bid = blockIdx.x;                 // l*TLUT + t
    int l = bid / TLUT, t = bid % TLUT;
    int h = threadIdx.x;                  // 64 threads
    __shared__ float h1s[HDIM];
    float len = (float)t * (CUT_R / (float)(TLUT - 1));
    float cut = 0.0f;
    if (len < CUT_R) cut = 0.5f * (cosf(len * (PI_F / CUT_R)) + 1.0f);
    float acc = rad_b1[l * HDIM + h];
    for (int b = 0; b < NBASIS; ++b) {
        float wb = fmaxf(widths[b], 0.1f);
        float center = (float)b * (CUT_R / (float)(NBASIS - 1));
        float d = (len - center) / wb;
        float rbf = __expf(-0.5f * d * d) * cut;
        acc += rbf * rad_w1[(l * NBASIS + b) * HDIM + h];
    }
    h1s[h] = siluf(acc);
    __syncthreads();
    float o = b2s[l * HDIM + h];
    const float* w2 = W2s + (size_t)l * HDIM * HDIM;
    for (int k = 0; k < HDIM; ++k) o += h1s[k] * w2[k * HDIM + h];
    lut[(size_t)bid * HDIM + h] = o;
}

// bf16 LUT rows for nearest-neighbor lookup: lutB[l][t][64]
__global__ void k_lutb(const float* __restrict__ lut, unsigned short* __restrict__ lutB) {
    int i = blockIdx.x * blockDim.x + threadIdx.x;          // L*TLUT*64
    if (i >= NLAYER * TLUT * HDIM) return;
    lutB[i] = (unsigned short)f2bf(lut[i]);
}

// ---------------- per-layer kernels ----------------

// one wave per node, 8 edge slots x 8 lanes (8 channels each via uint4 loads).
// Nearest-neighbor LUT (TLUT=256, L1-resident).
__global__ __launch_bounds__(256) void k_agg(const uint4* __restrict__ featsbf4,
                                             const uint4* __restrict__ lutB4_l,
                                             const int* __restrict__ starts,
                                             const unsigned int* __restrict__ erec,
                                             uint4* __restrict__ aggbf4) {
    int wid  = (blockIdx.x * blockDim.x + threadIdx.x) >> 6;
    int lane = threadIdx.x & 63;
    int slot = lane >> 3;     // 0..7
    int j    = lane & 7;      // channel octet
    if (wid >= N_NODES) return;
    int e0 = starts[wid], e1 = starts[wid + 1];
    float a0 = 0, a1 = 0, a2 = 0, a3 = 0, a4 = 0, a5 = 0, a6 = 0, a7 = 0;
    #pragma unroll 2
    for (int e = e0 + slot; e < e1; e += 8) {
        unsigned int rec = erec[e];
        int c  = rec >> 16;
        int i0 = (rec >> 8) & 255;
        uint4 qw = lutB4_l[i0 * 8 + j];
        uint4 fb = featsbf4[(size_t)c * 8 + j];
        a0 += bf_lo(fb.x) * bf_lo(qw.x);
        a1 += bf_hi(fb.x) * bf_hi(qw.x);
        a2 += bf_lo(fb.y) * bf_lo(qw.y);
        a3 += bf_hi(fb.y) * bf_hi(qw.y);
        a4 += bf_lo(fb.z) * bf_lo(qw.z);
        a5 += bf_hi(fb.z) * bf_hi(qw.z);
        a6 += bf_lo(fb.w) * bf_lo(qw.w);
        a7 += bf_hi(fb.w) * bf_hi(qw.w);
    }
    #pragma unroll
    for (int off = 8; off < 64; off <<= 1) {
        a0 += __shfl_xor(a0, off, 64);  a1 += __shfl_xor(a1, off, 64);
        a2 += __shfl_xor(a2, off, 64);  a3 += __shfl_xor(a3, off, 64);
        a4 += __shfl_xor(a4, off, 64);  a5 += __shfl_xor(a5, off, 64);
        a6 += __shfl_xor(a6, off, 64);  a7 += __shfl_xor(a7, off, 64);
    }
    if (slot == 0) {
        uint4 o;
        o.x = f2bf(a0) | (f2bf(a1) << 16);
        o.y = f2bf(a2) | (f2bf(a3) << 16);
        o.z = f2bf(a4) | (f2bf(a5) << 16);
        o.w = f2bf(a6) | (f2bf(a7) << 16);
        aggbf4[(size_t)wid * 8 + j] = o;
    }
}

// k_node v3 (MFMA): 64 nodes/block, 4 waves; wave w owns node rows [16w,16w+16).
constexpr int BP = 72;                     // bf16 LDS row pitch
__global__ __launch_bounds__(256) void k_node(float* __restrict__ feats,
        unsigned short* __restrict__ featsbf,
        const unsigned short* __restrict__ aggbf,
        const unsigned short* __restrict__ WspT_l, const unsigned short* __restrict__ PbT_l,
        const unsigned short* __restrict__ W1T_l, const unsigned short* __restrict__ W2T_l,
        const float* __restrict__ bsp_l,
        const float* __restrict__ mlp_b1_l, const float* __restrict__ mlp_b2_l,
        const float* __restrict__ ln_g_l, const float* __restrict__ ln_b_l) {
    __shared__ unsigned short P[64 * BP];   // x -> conv
    __shared__ unsigned short Q[64 * BP];   // a -> m1_lo
    __shared__ unsigned short S[64 * BP];   // m1_hi
    const int tid  = threadIdx.x;
    const int lane = tid & 63;
    const int wib  = tid >> 6;
    const int mt   = __builtin_amdgcn_readfirstlane(wib);
    const int nb0  = blockIdx.x * 64;
    const int colL = lane & 15;
    const int kgrp = lane >> 4;

    #pragma unroll 4
    for (int i = 0; i < 16; ++i) {
        int r  = wib + i * 4;
        int nd = nb0 + r; nd = (nd < N_NODES) ? nd : (N_NODES - 1);
        P[r * BP + lane] = featsbf[(size_t)nd * 64 + lane];
        Q[r * BP + lane] = aggbf[(size_t)nd * 64 + lane];
    }
    __syncthreads();

    // ---- conv = x@Wsp + a@Pb + bsp ----
    f32x4 acc[4];
    #pragma unroll
    for (int nt = 0; nt < 4; ++nt) {
        float b = bsp_l[nt * 16 + colL];
        acc[nt][0] = b; acc[nt][1] = b; acc[nt][2] = b; acc[nt][3] = b;
    }
    #pragma unroll
    for (int kb = 0; kb < 2; ++kb) {
        short8 ax = *(const short8*)&P[(mt * 16 + colL) * BP + kb * 32 + kgrp * 8];
        short8 aa = *(const short8*)&Q[(mt * 16 + colL) * BP + kb * 32 + kgrp * 8];
        #pragma unroll
        for (int nt = 0; nt < 4; ++nt) {
            short8 bw = *(const short8*)&WspT_l[(nt * 16 + colL) * 64 + kb * 32 + kgrp * 8];
            acc[nt] = MFMA16(ax, bw, acc[nt], 0, 0, 0);
            short8 bp = *(const short8*)&PbT_l[(nt * 16 + colL) * 64 + kb * 32 + kgrp * 8];
            acc[nt] = MFMA16(aa, bp, acc[nt], 0, 0, 0);
        }
    }
    __syncthreads();
    #pragma unroll
    for (int nt = 0; nt < 4; ++nt)
        #pragma unroll
        for (int j = 0; j < 4; ++j)
            P[(mt * 16 + kgrp * 4 + j) * BP + nt * 16 + colL] = (unsigned short)f2bf(acc[nt][j]);
    __syncthreads();

    // ---- m1 = silu(conv@W1 + b1), 128 wide ----
    {
        f32x4 m[8];
        #pragma unroll
        for (int nt = 0; nt < 8; ++nt) {
            float b = mlp_b1_l[nt * 16 + colL];
            m[nt][0] = b; m[nt][1] = b; m[nt][2] = b; m[nt][3] = b;
        }
        #pragma unroll
        for (int kb = 0; kb < 2; ++kb) {
            short8 ac = *(const short8*)&P[(mt * 16 + colL) * BP + kb * 32 + kgrp * 8];
            #pragma unroll
            for (int nt = 0; nt < 8; ++nt) {
                short8 bw = *(const short8*)&W1T_l[(nt * 16 + colL) * 64 + kb * 32 + kgrp * 8];
                m[nt] = MFMA16(ac, bw, m[nt], 0, 0, 0);
            }
        }
        __syncthreads();
        #pragma unroll
        for (int nt = 0; nt < 4; ++nt)
            #pragma unroll
            for (int j = 0; j < 4; ++j)
                Q[(mt * 16 + kgrp * 4 + j) * BP + nt * 16 + colL] =
                    (unsigned short)f2bf(siluf(m[nt][j]));
        #pragma unroll
        for (int nt = 4; nt < 8; ++nt)
            #pragma unroll
            for (int j = 0; j < 4; ++j)
                S[(mt * 16 + kgrp * 4 + j) * BP + (nt - 4) * 16 + colL] =
                    (unsigned short)f2bf(siluf(m[nt][j]));
    }
    __syncthreads();

    // ---- upd = m1@W2 + b2 ----
    f32x4 u[4];
    #pragma unroll
    for (int nt = 0; nt < 4; ++nt) {
        float b = mlp_b2_l[nt * 16 + colL];
        u[nt][0] = b; u[nt][1] = b; u[nt][2] = b; u[nt][3] = b;
    }
    #pragma unroll
    for (int kb = 0; kb < 4; ++kb) {
        short8 am = (kb < 2)
            ? *(const short8*)&Q[(mt * 16 + colL) * BP + kb * 32 + kgrp * 8]
            : *(const short8*)&S[(mt * 16 + colL) * BP + (kb - 2) * 32 + kgrp * 8];
        #pragma unroll
        for (int nt = 0; nt < 4; ++nt) {
            short8 bw = *(const short8*)&W2T_l[(nt * 16 + colL) * 128 + kb * 32 + kgrp * 8];
            u[nt] = MFMA16(am, bw, u[nt], 0, 0, 0);
        }
    }

    // ---- residual + LayerNorm ----
    float y[4][4];
    float s1[4] = {0, 0, 0, 0}, s2[4] = {0, 0, 0, 0};
    #pragma unroll
    for (int j = 0; j < 4; ++j) {
        int node = nb0 + mt * 16 + kgrp * 4 + j;
        int nds  = (node < N_NODES) ? node : (N_NODES - 1);
        #pragma unroll
        for (int nt = 0; nt < 4; ++nt) {
            float v = feats[(size_t)nds * 64 + nt * 16 + colL] + u[nt][j];
            y[nt][j] = v;
            s1[j] += v; s2[j] += v * v;
        }
    }
    #pragma unroll
    for (int off = 1; off < 16; off <<= 1) {
        #pragma unroll
        for (int j = 0; j < 4; ++j) {
            s1[j] += __shfl_xor(s1[j], off, 64);
            s2[j] += __shfl_xor(s2[j], off, 64);
        }
    }
    float gv[4], bv[4];
    #pragma unroll
    for (int nt = 0; nt < 4; ++nt) {
        gv[nt] = ln_g_l[nt * 16 + colL];
        bv[nt] = ln_b_l[nt * 16 + colL];
    }
    #pragma unroll
    for (int j = 0; j < 4; ++j) {
        int node = nb0 + mt * 16 + kgrp * 4 + j;
        if (node >= N_NODES) continue;
        float mu  = s1[j] * (1.0f / 64.0f);
        float var = s2[j] * (1.0f / 64.0f) - mu * mu;
        float rr  = rsqrtf(var + 1e-5f);
        #pragma unroll
        for (int nt = 0; nt < 4; ++nt) {
            float o = (y[nt][j] - mu) * rr * gv[nt] + bv[nt];
            feats[(size_t)node * 64 + nt * 16 + colL]   = o;
            featsbf[(size_t)node * 64 + nt * 16 + colL] = (unsigned short)f2bf(o);
        }
    }
}

// ---------------- readout (MFMA, k_node template) ----------------

__global__ __launch_bounds__(256) void k_readout(const unsigned short* __restrict__ featsbf,
        const int* __restrict__ an,
        const unsigned short* __restrict__ Ro1T, const unsigned short* __restrict__ Ro2T,
        const float* __restrict__ ro_b1, const float* __restrict__ ro_b2,
        const float* __restrict__ ro_w3, const float* __restrict__ ro_b3,
        const float* __restrict__ atomic_e, float* __restrict__ blockpart) {
    __shared__ unsigned short P[64 * BP];   // feats
    __shared__ unsigned short Q[64 * BP];   // h1
    __shared__ float sred[256];
    const int tid  = threadIdx.x;
    const int lane = tid & 63;
    const int wib  = tid >> 6;
    const int mt   = __builtin_amdgcn_readfirstlane(wib);
    const int nb0  = blockIdx.x * 64;
    const int colL = lane & 15;
    const int kgrp = lane >> 4;

    #pragma unroll 4
    for (int i = 0; i < 16; ++i) {
        int r  = wib + i * 4;
        int nd = nb0 + r; nd = (nd < N_NODES) ? nd : (N_NODES - 1);
        P[r * BP + lane] = featsbf[(size_t)nd * 64 + lane];
    }
    __syncthreads();

    // ---- h1 = silu(x @ Ro1 + b1) ----
    {
        f32x4 m[4];
        #pragma unroll
        for (int nt = 0; nt < 4; ++nt) {
            float b = ro_b1[nt * 16 + colL];
            m[nt][0] = b; m[nt][1] = b; m[nt][2] = b; m[nt][3] = b;
        }
        #pragma unroll
        for (int kb = 0; kb < 2; ++kb) {
            short8 ax = *(const short8*)&P[(mt * 16 + colL) * BP + kb * 32 + kgrp * 8];
            #pragma unroll
            for (int nt = 0; nt < 4; ++nt) {
                short8 bw = *(const short8*)&Ro1T[(nt * 16 + colL) * 64 + kb * 32 + kgrp * 8];
                m[nt] = MFMA16(ax, bw, m[nt], 0, 0, 0);
            }
        }
        __syncthreads();
        #pragma unroll
        for (int nt = 0; nt < 4; ++nt)
            #pragma unroll
            for (int j = 0; j < 4; ++j)
                Q[(mt * 16 + kgrp * 4 + j) * BP + nt * 16 + colL] =
                    (unsigned short)f2bf(siluf(m[nt][j]));
    }
    __syncthreads();

    // ---- h2 = silu(h1 @ Ro2 + b2), 32 wide; e = h2 @ ro_w3 ----
    f32x4 u[2];
    #pragma unroll
    for (int nt = 0; nt < 2; ++nt) {
        float b = ro_b2[nt * 16 + colL];
        u[nt][0] = b; u[nt][1] = b; u[nt][2] = b; u[nt][3] = b;
    }
    #pragma unroll
    for (int kb = 0; kb < 2; ++kb) {
        short8 am = *(const short8*)&Q[(mt * 16 + colL) * BP + kb * 32 + kgrp * 8];
        #pragma unroll
        for (int nt = 0; nt < 2; ++nt) {
            short8 bw = *(const short8*)&Ro2T[(nt * 16 + colL) * 64 + kb * 32 + kgrp * 8];
            u[nt] = MFMA16(am, bw, u[nt], 0, 0, 0);
        }
    }
    float w3[2];
    #pragma unroll
    for (int nt = 0; nt < 2; ++nt) w3[nt] = ro_w3[nt * 16 + colL];
    float part = 0.0f;
    #pragma unroll
    for (int j = 0; j < 4; ++j) {
        float c = siluf(u[0][j]) * w3[0] + siluf(u[1][j]) * w3[1];
        #pragma unroll
        for (int off = 1; off < 16; off <<= 1) c += __shfl_xor(c, off, 64);
        int node = nb0 + mt * 16 + kgrp * 4 + j;
        if (colL == 0 && node < N_NODES)
            part += c + ro_b3[0] + atomic_e[an[node]];
    }
    sred[tid] = part;
    __syncthreads();
    for (int off = 128; off > 0; off >>= 1) {
        if (tid < off) sred[tid] += sred[tid + off];
        __syncthreads();
    }
    if (tid == 0) blockpart[blockIdx.x] = sred[0];
}

__global__ void k_final(const float* __restrict__ blockpart, int nb, float* __restrict__ out) {
    __shared__ float s[256];
    float acc = 0.f;
    for (int i = threadIdx.x; i < nb; i += 256) acc += blockpart[i];
    s[threadIdx.x] = acc; __syncthreads();
    for (int off = 128; off > 0; off >>= 1) {
        if (threadIdx.x < off) s[threadIdx.x] += s[threadIdx.x + off];
        __syncthreads();
    }
    if (threadIdx.x == 0) out[0] = s[0];
}

// ---------------- launch ----------------

extern "C" void kernel_launch(void* const* d_in, const int* in_sizes, int n_in,
                              void* d_out, int out_size, void* d_ws, size_t ws_size,
                              hipStream_t stream) {
    const int*   an       = (const int*)  d_in[0];
    const float* pos      = (const float*)d_in[1];
    const int*   edge     = (const int*)  d_in[2];
    const float* widths   = (const float*)d_in[3];
    const float* embed    = (const float*)d_in[4];
    const float* rad_w1   = (const float*)d_in[5];
    const float* rad_b1   = (const float*)d_in[6];
    const float* rad_w2   = (const float*)d_in[7];
    const float* rad_b2   = (const float*)d_in[8];
    const float* self_w   = (const float*)d_in[9];
    const float* self_b   = (const float*)d_in[10];
    const float* proj_w   = (const float*)d_in[11];
    const float* proj_b   = (const float*)d_in[12];
    const float* mlp_w1   = (const float*)d_in[13];
    const float* mlp_b1   = (const float*)d_in[14];
    const float* mlp_w2   = (const float*)d_in[15];
    const float* mlp_b2   = (const float*)d_in[16];
    const float* ln_g     = (const float*)d_in[17];
    const float* ln_b     = (const float*)d_in[18];
    const float* ro_w1    = (const float*)d_in[19];
    const float* ro_b1    = (const float*)d_in[20];
    const float* ro_w2    = (const float*)d_in[21];
    const float* ro_b2    = (const float*)d_in[22];
    const float* ro_w3    = (const float*)d_in[23];
    const float* ro_b3    = (const float*)d_in[24];
    const float* atomic_e = (const float*)d_in[25];

    char* w = (char*)d_ws;
    auto alloc = [&](size_t bytes) { char* p = w; w += (bytes + 255) & ~(size_t)255; return p; };
    float* feats     = (float*)alloc(sizeof(float) * N_NODES * HDIM);
    unsigned short* featsbf = (unsigned short*)alloc(sizeof(unsigned short) * N_NODES * HDIM);
    unsigned short* aggbf   = (unsigned short*)alloc(sizeof(unsigned short) * N_NODES * HDIM);
    float* lut       = (float*)alloc(sizeof(float) * NLAYER * TLUT * HDIM);
    unsigned short* lutB = (unsigned short*)alloc(sizeof(unsigned short) * NLAYER * TLUT * HDIM);
    float* W2s       = (float*)alloc(sizeof(float) * NLAYER * HDIM * HDIM);
    float* b2s       = (float*)alloc(sizeof(float) * NLAYER * HDIM);
    float* Wsp       = (float*)alloc(sizeof(float) * NLAYER * HDIM * HDIM);
    float* bsp       = (float*)alloc(sizeof(float) * NLAYER * HDIM);
    unsigned short* WspT = (unsigned short*)alloc(sizeof(unsigned short) * NLAYER * 4096);
    unsigned short* PbT  = (unsigned short*)alloc(sizeof(unsigned short) * NLAYER * 4096);
    unsigned short* W1T  = (unsigned short*)alloc(sizeof(unsigned short) * NLAYER * 8192);
    unsigned short* W2T  = (unsigned short*)alloc(sizeof(unsigned short) * NLAYER * 8192);
    unsigned short* Ro1T = (unsigned short*)alloc(sizeof(unsigned short) * 4096);
    unsigned short* Ro2T = (unsigned short*)alloc(sizeof(unsigned short) * 2048);
    unsigned int* erec = (unsigned int*)alloc(sizeof(unsigned int) * N_EDGES);
    unsigned int* binned = (unsigned int*)alloc(sizeof(unsigned int) * (size_t)NBKT * BCAP);
    int*   btail     = (int*)  alloc(sizeof(int) * 256);
    int*   bbase     = (int*)  alloc(sizeof(int) * 256);
    int*   starts    = (int*)  alloc(sizeof(int) * (N_NODES + 1));
    float* blockpart = (float*)alloc(sizeof(float) * 1024);
    (void)ws_size; (void)in_sizes; (void)n_in; (void)out_size;

    const int* erow = edge;
    const int* ecol = edge + N_EDGES;

    hipMemsetAsync(btail, 0, sizeof(int) * 256, stream);
    k_embed<<<12500, 256, 0, stream>>>(an, embed, feats, featsbf);
    k_binA<<<(N_EDGES + TILE - 1) / TILE, 256, 0, stream>>>(erow, ecol, pos, btail, binned);
    k_scanB<<<1, 256, 0, stream>>>(btail, bbase);
    k_binB<<<NBKT, 256, 0, stream>>>(binned, btail, bbase, starts, erec);
    k_prep<<<80, 256, 0, stream>>>(rad_w2, self_w, proj_w, W2s, Wsp);
    k_wtr<<<(NLAYER * 24576 + 255) / 256, 256, 0, stream>>>(Wsp, proj_w, mlp_w1, mlp_w2,
                                                            WspT, PbT, W1T, W2T);
    k_rotr<<<24, 256, 0, stream>>>(ro_w1, ro_w2, Ro1T, Ro2T);
    k_bias<<<5, 64, 0, stream>>>(rad_b2, self_b, proj_w, proj_b, b2s, bsp);
    k_lut<<<NLAYER * TLUT, 64, 0, stream>>>(widths, rad_w1, rad_b1, W2s, b2s, lut);
    k_lutb<<<(NLAYER * TLUT * HDIM + 255) / 256, 256, 0, stream>>>(lut, lutB);

    for (int l = 0; l < NLAYER; ++l) {
        k_agg<<<12500, 256, 0, stream>>>((const uint4*)featsbf,
                                         (const uint4*)(lutB + (size_t)l * TLUT * HDIM),
                                         starts, erec, (uint4*)aggbf);
        k_node<<<782, 256, 0, stream>>>(feats, featsbf, aggbf,
            WspT + (size_t)l * 4096, PbT + (size_t)l * 4096,
            W1T + (size_t)l * 8192, W2T + (size_t)l * 8192,
            bsp + l * HDIM, mlp_b1 + l * 2 * HDIM, mlp_b2 + l * HDIM,
            ln_g + l * HDIM, ln_b + l * HDIM);
    }

    k_readout<<<782, 256, 0, stream>>>(featsbf, an, Ro1T, Ro2T, ro_b1, ro_b2,
                                       ro_w3, ro_b3, atomic_e, blockpart);
    k_final<<<1, 256, 0, stream>>>(blockpart, 782, (float*)d_out);
}

// Round 19
// 403.173 us; speedup vs baseline: 1.1106x; 1.0213x over previous
//
#include <hip/hip_runtime.h>
#include <math.h>

// Problem constants (from reference)
constexpr int N_NODES = 50000;
constexpr int N_EDGES = 1600000;
constexpr int HDIM    = 64;
constexpr int NLAYER  = 5;
constexpr int NBASIS  = 8;
constexpr int TLUT    = 256;           // radial LUT entries (8-bit index)
constexpr float CUT_R = 5.0f;
constexpr float PI_F  = 3.14159265358979f;

// binned scatter: buckets of 256 nodes (r >> 8)
constexpr int NBKT = 196;
constexpr int BCAP = 9216;             // mean 8192 + ~11 sigma
constexpr int TILE = 2048;

typedef __attribute__((ext_vector_type(8))) short short8;   // 8 bf16 (4 VGPRs)
typedef __attribute__((ext_vector_type(4))) float f32x4;    // MFMA acc
#define MFMA16 __builtin_amdgcn_mfma_f32_16x16x32_bf16

__device__ __forceinline__ float siluf(float x) { return x / (1.0f + __expf(-x)); }

// round-to-nearest-even f32 -> bf16 bits
__device__ __forceinline__ unsigned int f2bf(float x) {
    unsigned int b = __float_as_uint(x);
    return (b + 0x7fffu + ((b >> 16) & 1u)) >> 16;
}
__device__ __forceinline__ float bf_lo(unsigned int u) { return __uint_as_float(u << 16); }
__device__ __forceinline__ float bf_hi(unsigned int u) { return __uint_as_float(u & 0xffff0000u); }

// block-wide exclusive scan of 256 values (one per thread) using wave shuffle
// scans + a 4-entry LDS combine. Returns exclusive prefix; 2 barriers total.
__device__ __forceinline__ int blockScan256Excl(int cv, int tid, int* wtot) {
    int v = cv;
    int lane = tid & 63;
    #pragma unroll
    for (int off = 1; off < 64; off <<= 1) {
        int t = __shfl_up(v, off, 64);
        if (lane >= off) v += t;
    }
    if (lane == 63) wtot[tid >> 6] = v;
    __syncthreads();
    int pre = 0;
    #pragma unroll
    for (int w = 0; w < 4; ++w)
        if (w < (tid >> 6)) pre += wtot[w];
    __syncthreads();
    return v + pre - cv;                 // exclusive
}

// ---------------- setup kernels ----------------

__global__ void k_embed(const int* __restrict__ an, const float* __restrict__ embed,
                        float* __restrict__ feats, unsigned short* __restrict__ featsbf) {
    int i = blockIdx.x * blockDim.x + threadIdx.x;           // N*H threads
    if (i >= N_NODES * HDIM) return;
    int node = i >> 6, h = i & 63;
    float v = embed[an[node] * HDIM + h];
    feats[i] = v;
    featsbf[i] = (unsigned short)f2bf(v);
}

// pass A: block-sort TILE-edge tiles by node bucket (r>>8), append runs to binned[]
// rec packs (col<<16) | (nn<<8) | (r&255): 4 bytes total
__global__ __launch_bounds__(256) void k_binA(const int* __restrict__ row,
                                              const int* __restrict__ col,
                                              const float* __restrict__ pos,
                                              int* __restrict__ btail,
                                              unsigned int* __restrict__ binned) {
    __shared__ unsigned int ent[TILE];    // 8 KB
    __shared__ short bb[TILE];            // 4 KB
    __shared__ unsigned int sorted[TILE]; // 8 KB
    __shared__ short sortedB[TILE];       // 4 KB
    __shared__ int cnt[256], cnt2[256], base[256], gbase[256];
    __shared__ int wtot[4];
    const int tid = threadIdx.x;
    const int t0  = blockIdx.x * TILE;
    const int nv  = min(TILE, N_EDGES - t0);

    cnt[tid] = 0;
    __syncthreads();

    #pragma unroll
    for (int i = 0; i < TILE / 256; ++i) {
        int idx = i * 256 + tid;
        if (idx < nv) {
            int e = t0 + idx;
            int r = row[e], c = col[e];
            float dx = pos[c * 3 + 0] - pos[r * 3 + 0];
            float dy = pos[c * 3 + 1] - pos[r * 3 + 1];
            float dz = pos[c * 3 + 2] - pos[r * 3 + 2];
            float len = sqrtf(dx * dx + dy * dy + dz * dz);
            float t = len * ((float)(TLUT - 1) / CUT_R);
            t = fminf(t, (float)(TLUT - 1));
            unsigned int nn = (unsigned int)(t + 0.5f);
            if (nn > TLUT - 1) nn = TLUT - 1;
            ent[idx] = ((unsigned int)c << 16) | (nn << 8) | ((unsigned int)r & 255u);
            int b = r >> 8;
            bb[idx] = (short)b;
            atomicAdd(&cnt[b], 1);
        }
    }
    __syncthreads();
    int cv = cnt[tid];
    int excl = blockScan256Excl(cv, tid, wtot);
    base[tid] = excl;
    if (tid < NBKT && cv > 0) gbase[tid] = atomicAdd(&btail[tid], cv);
    cnt2[tid] = excl;
    __syncthreads();
    #pragma unroll
    for (int i = 0; i < TILE / 256; ++i) {
        int idx = i * 256 + tid;
        if (idx < nv) {
            int b = bb[idx];
            int p = atomicAdd(&cnt2[b], 1);
            sorted[p]  = ent[idx];
            sortedB[p] = (short)b;
        }
    }
    __syncthreads();
    for (int s = tid; s < nv; s += 256) {
        int b = sortedB[s];
        binned[(size_t)b * BCAP + gbase[b] + (s - base[b])] = sorted[s];
    }
}

// exclusive scan of 196 bucket totals (1 block, 256 threads)
__global__ void k_scanB(const int* __restrict__ btail, int* __restrict__ bbase) {
    __shared__ int wtot[4];
    int t = threadIdx.x;
    int v = (t < NBKT) ? btail[t] : 0;
    int excl = blockScan256Excl(v, t, wtot);
    if (t < NBKT) bbase[t] = excl;
}

// pass B: one block per 256-node bucket. LDS histogram -> wave scan -> starts ->
// scatter erec via LDS cursors. No global atomics.
__global__ __launch_bounds__(256) void k_binB(const unsigned int* __restrict__ binned,
                                              const int* __restrict__ btail,
                                              const int* __restrict__ bbase,
                                              int* __restrict__ starts,
                                              unsigned int* __restrict__ erec) {
    __shared__ int hist[256];
    __shared__ int cur[256];
    __shared__ int wtot[4];
    const int b = blockIdx.x;
    const int node0 = b << 8;
    const int t = threadIdx.x;
    hist[t] = 0;
    __syncthreads();
    const int cnt = btail[b];
    const unsigned int* src = binned + (size_t)b * BCAP;
    for (int s = t; s < cnt; s += 256)
        atomicAdd(&hist[src[s] & 255u], 1);
    __syncthreads();
    int h = hist[t];
    int excl = bbase[b] + blockScan256Excl(h, t, wtot);
    int n = node0 + t;
    if (n < N_NODES) starts[n] = excl;
    if (b == 0 && t == 0) starts[N_NODES] = N_EDGES;
    cur[t] = excl;
    __syncthreads();
    for (int s = t; s < cnt; s += 256) {
        unsigned int p = src[s];
        int pp = atomicAdd(&cur[p & 255u], 1);
        erec[pp] = p;
    }
}

// fused: W2s/Wsp (i < L*4096) + biases b2s/bsp (remainder)
__global__ void k_prep(const float* __restrict__ rad_w2, const float* __restrict__ self_w,
                       const float* __restrict__ proj_w,
                       const float* __restrict__ rad_b2, const float* __restrict__ self_b,
                       const float* __restrict__ proj_b,
                       float* __restrict__ W2s, float* __restrict__ Wsp,
                       float* __restrict__ b2s, float* __restrict__ bsp) {
    int i = blockIdx.x * blockDim.x + threadIdx.x;
    if (i < NLAYER * HDIM * HDIM) {
        int l = i / (HDIM * HDIM); int rem = i % (HDIM * HDIM);
        int k = rem / HDIM; int h = rem % HDIM;
        const float* w = rad_w2 + ((size_t)l * HDIM + k) * (HDIM * 3) + h * 3;
        W2s[i] = w[0] + w[1] + w[2];
        const float* sw = self_w + ((size_t)l * HDIM + k) * HDIM;
        const float* pw = proj_w + (size_t)l * 2 * HDIM * HDIM;
        float acc = 0.f;
        for (int m = 0; m < HDIM; ++m) acc += sw[m] * pw[m * HDIM + h];
        Wsp[i] = acc;
    } else {
        int i2 = i - NLAYER * HDIM * HDIM;
        if (i2 >= NLAYER * HDIM) return;
        int l = i2 / HDIM, h = i2 % HDIM;
        const float* rb2 = rad_b2 + l * HDIM * 3 + h * 3;
        b2s[i2] = rb2[0] + rb2[1] + rb2[2];
        float acc = proj_b[l * HDIM + h];
        const float* pw = proj_w + (size_t)l * 2 * HDIM * HDIM;
        const float* sb = self_b + l * HDIM;
        for (int m = 0; m < HDIM; ++m) acc += sb[m] * pw[m * HDIM + h];
        bsp[i2] = acc;
    }
}

// fused: bf16 transposed weights for MFMA B-operands + readout weights
__global__ void k_wtr(const float* __restrict__ Wsp, const float* __restrict__ proj_w,
                      const float* __restrict__ mlp_w1, const float* __restrict__ mlp_w2,
                      const float* __restrict__ ro_w1, const float* __restrict__ ro_w2,
                      unsigned short* __restrict__ WspT, unsigned short* __restrict__ PbT,
                      unsigned short* __restrict__ W1T, unsigned short* __restrict__ W2T,
                      unsigned short* __restrict__ Ro1T, unsigned short* __restrict__ Ro2T) {
    int i = blockIdx.x * blockDim.x + threadIdx.x;
    if (i < NLAYER * 24576) {
        int l = i / 24576, off = i % 24576;
        if (off < 4096) {
            int n = off >> 6, k = off & 63;
            WspT[(size_t)l * 4096 + off] = (unsigned short)f2bf(Wsp[(size_t)l * 4096 + k * 64 + n]);
        } else if (off < 8192) {
            int o = off - 4096; int n = o >> 6, k = o & 63;
            PbT[(size_t)l * 4096 + o] =
                (unsigned short)f2bf(proj_w[(size_t)l * 8192 + (64 + k) * 64 + n]);
        } else if (off < 16384) {
            int o = off - 8192; int n = o >> 6, k = o & 63;
            W1T[(size_t)l * 8192 + o] = (unsigned short)f2bf(mlp_w1[(size_t)l * 8192 + k * 128 + n]);
        } else {
            int o = off - 16384; int n = o >> 7, k = o & 127;
            W2T[(size_t)l * 8192 + o] = (unsigned short)f2bf(mlp_w2[(size_t)l * 8192 + k * 64 + n]);
        }
    } else {
        int i2 = i - NLAYER * 24576;
        if (i2 >= 6144) return;
        if (i2 < 4096) {
            int n = i2 >> 6, k = i2 & 63;
            Ro1T[i2] = (unsigned short)f2bf(ro_w1[k * 64 + n]);
        } else {
            int o = i2 - 4096; int n = o >> 6, k = o & 63;
            Ro2T[o] = (unsigned short)f2bf(ro_w2[k * 32 + n]);
        }
    }
}

// radial LUT -> bf16 directly
__global__ void k_lut(const float* __restrict__ widths, const float* __restrict__ rad_w1,
                      const float* __restrict__ rad_b1, const float* __restrict__ W2s,
                      const float* __restrict__ b2s, unsigned short* __restrict__ lutB) {
    int bid = blockIdx.x;                 // l*TLUT + t
    int l = bid / TLUT, t = bid % TLUT;
    int h = threadIdx.x;                  // 64 threads
    __shared__ float h1s[HDIM];
    float len = (float)t * (CUT_R / (float)(TLUT - 1));
    float cut = 0.0f;
    if (len < CUT_R) cut = 0.5f * (cosf(len * (PI_F / CUT_R)) + 1.0f);
    float acc = rad_b1[l * HDIM + h];
    for (int b = 0; b < NBASIS; ++b) {
        float wb = fmaxf(widths[b], 0.1f);
        float center = (float)b * (CUT_R / (float)(NBASIS - 1));
        float d = (len - center) / wb;
        float rbf = __expf(-0.5f * d * d) * cut;
        acc += rbf * rad_w1[(l * NBASIS + b) * HDIM + h];
    }
    h1s[h] = siluf(acc);
    __syncthreads();
    float o = b2s[l * HDIM + h];
    const float* w2 = W2s + (size_t)l * HDIM * HDIM;
    for (int k = 0; k < HDIM; ++k) o += h1s[k] * w2[k * HDIM + h];
    lutB[(size_t)bid * HDIM + h] = (unsigned short)f2bf(o);
}

// ---------------- per-layer kernels ----------------

// one wave per node, 8 edge slots x 8 lanes (8 channels each via uint4 loads).
// Nearest-neighbor LUT (TLUT=256, L1-resident).
__global__ __launch_bounds__(256) void k_agg(const uint4* __restrict__ featsbf4,
                                             const uint4* __restrict__ lutB4_l,
                                             const int* __restrict__ starts,
                                             const unsigned int* __restrict__ erec,
                                             uint4* __restrict__ aggbf4) {
    int wid  = (blockIdx.x * blockDim.x + threadIdx.x) >> 6;
    int lane = threadIdx.x & 63;
    int slot = lane >> 3;     // 0..7
    int j    = lane & 7;      // channel octet
    if (wid >= N_NODES) return;
    int e0 = starts[wid], e1 = starts[wid + 1];
    float a0 = 0, a1 = 0, a2 = 0, a3 = 0, a4 = 0, a5 = 0, a6 = 0, a7 = 0;
    #pragma unroll 2
    for (int e = e0 + slot; e < e1; e += 8) {
        unsigned int rec = erec[e];
        int c  = rec >> 16;
        int i0 = (rec >> 8) & 255;
        uint4 qw = lutB4_l[i0 * 8 + j];
        uint4 fb = featsbf4[(size_t)c * 8 + j];
        a0 += bf_lo(fb.x) * bf_lo(qw.x);
        a1 += bf_hi(fb.x) * bf_hi(qw.x);
        a2 += bf_lo(fb.y) * bf_lo(qw.y);
        a3 += bf_hi(fb.y) * bf_hi(qw.y);
        a4 += bf_lo(fb.z) * bf_lo(qw.z);
        a5 += bf_hi(fb.z) * bf_hi(qw.z);
        a6 += bf_lo(fb.w) * bf_lo(qw.w);
        a7 += bf_hi(fb.w) * bf_hi(qw.w);
    }
    #pragma unroll
    for (int off = 8; off < 64; off <<= 1) {
        a0 += __shfl_xor(a0, off, 64);  a1 += __shfl_xor(a1, off, 64);
        a2 += __shfl_xor(a2, off, 64);  a3 += __shfl_xor(a3, off, 64);
        a4 += __shfl_xor(a4, off, 64);  a5 += __shfl_xor(a5, off, 64);
        a6 += __shfl_xor(a6, off, 64);  a7 += __shfl_xor(a7, off, 64);
    }
    if (slot == 0) {
        uint4 o;
        o.x = f2bf(a0) | (f2bf(a1) << 16);
        o.y = f2bf(a2) | (f2bf(a3) << 16);
        o.z = f2bf(a4) | (f2bf(a5) << 16);
        o.w = f2bf(a6) | (f2bf(a7) << 16);
        aggbf4[(size_t)wid * 8 + j] = o;
    }
}

// k_node v3 (MFMA): 64 nodes/block, 4 waves; wave w owns node rows [16w,16w+16).
constexpr int BP = 72;                     // bf16 LDS row pitch
__global__ __launch_bounds__(256) void k_node(float* __restrict__ feats,
        unsigned short* __restrict__ featsbf,
        const unsigned short* __restrict__ aggbf,
        const unsigned short* __restrict__ WspT_l, const unsigned short* __restrict__ PbT_l,
        const unsigned short* __restrict__ W1T_l, const unsigned short* __restrict__ W2T_l,
        const float* __restrict__ bsp_l,
        const float* __restrict__ mlp_b1_l, const float* __restrict__ mlp_b2_l,
        const float* __restrict__ ln_g_l, const float* __restrict__ ln_b_l) {
    __shared__ unsigned short P[64 * BP];   // x -> conv
    __shared__ unsigned short Q[64 * BP];   // a -> m1_lo
    __shared__ unsigned short S[64 * BP];   // m1_hi
    const int tid  = threadIdx.x;
    const int lane = tid & 63;
    const int wib  = tid >> 6;
    const int mt   = __builtin_amdgcn_readfirstlane(wib);
    const int nb0  = blockIdx.x * 64;
    const int colL = lane & 15;
    const int kgrp = lane >> 4;

    #pragma unroll 4
    for (int i = 0; i < 16; ++i) {
        int r  = wib + i * 4;
        int nd = nb0 + r; nd = (nd < N_NODES) ? nd : (N_NODES - 1);
        P[r * BP + lane] = featsbf[(size_t)nd * 64 + lane];
        Q[r * BP + lane] = aggbf[(size_t)nd * 64 + lane];
    }
    __syncthreads();

    // ---- conv = x@Wsp + a@Pb + bsp ----
    f32x4 acc[4];
    #pragma unroll
    for (int nt = 0; nt < 4; ++nt) {
        float b = bsp_l[nt * 16 + colL];
        acc[nt][0] = b; acc[nt][1] = b; acc[nt][2] = b; acc[nt][3] = b;
    }
    #pragma unroll
    for (int kb = 0; kb < 2; ++kb) {
        short8 ax = *(const short8*)&P[(mt * 16 + colL) * BP + kb * 32 + kgrp * 8];
        short8 aa = *(const short8*)&Q[(mt * 16 + colL) * BP + kb * 32 + kgrp * 8];
        #pragma unroll
        for (int nt = 0; nt < 4; ++nt) {
            short8 bw = *(const short8*)&WspT_l[(nt * 16 + colL) * 64 + kb * 32 + kgrp * 8];
            acc[nt] = MFMA16(ax, bw, acc[nt], 0, 0, 0);
            short8 bp = *(const short8*)&PbT_l[(nt * 16 + colL) * 64 + kb * 32 + kgrp * 8];
            acc[nt] = MFMA16(aa, bp, acc[nt], 0, 0, 0);
        }
    }
    __syncthreads();
    #pragma unroll
    for (int nt = 0; nt < 4; ++nt)
        #pragma unroll
        for (int j = 0; j < 4; ++j)
            P[(mt * 16 + kgrp * 4 + j) * BP + nt * 16 + colL] = (unsigned short)f2bf(acc[nt][j]);
    __syncthreads();

    // ---- m1 = silu(conv@W1 + b1), 128 wide ----
    {
        f32x4 m[8];
        #pragma unroll
        for (int nt = 0; nt < 8; ++nt) {
            float b = mlp_b1_l[nt * 16 + colL];
            m[nt][0] = b; m[nt][1] = b; m[nt][2] = b; m[nt][3] = b;
        }
        #pragma unroll
        for (int kb = 0; kb < 2; ++kb) {
            short8 ac = *(const short8*)&P[(mt * 16 + colL) * BP + kb * 32 + kgrp * 8];
            #pragma unroll
            for (int nt = 0; nt < 8; ++nt) {
                short8 bw = *(const short8*)&W1T_l[(nt * 16 + colL) * 64 + kb * 32 + kgrp * 8];
                m[nt] = MFMA16(ac, bw, m[nt], 0, 0, 0);
            }
        }
        __syncthreads();
        #pragma unroll
        for (int nt = 0; nt < 4; ++nt)
            #pragma unroll
            for (int j = 0; j < 4; ++j)
                Q[(mt * 16 + kgrp * 4 + j) * BP + nt * 16 + colL] =
                    (unsigned short)f2bf(siluf(m[nt][j]));
        #pragma unroll
        for (int nt = 4; nt < 8; ++nt)
            #pragma unroll
            for (int j = 0; j < 4; ++j)
                S[(mt * 16 + kgrp * 4 + j) * BP + (nt - 4) * 16 + colL] =
                    (unsigned short)f2bf(siluf(m[nt][j]));
    }
    __syncthreads();

    // ---- upd = m1@W2 + b2 ----
    f32x4 u[4];
    #pragma unroll
    for (int nt = 0; nt < 4; ++nt) {
        float b = mlp_b2_l[nt * 16 + colL];
        u[nt][0] = b; u[nt][1] = b; u[nt][2] = b; u[nt][3] = b;
    }
    #pragma unroll
    for (int kb = 0; kb < 4; ++kb) {
        short8 am = (kb < 2)
            ? *(const short8*)&Q[(mt * 16 + colL) * BP + kb * 32 + kgrp * 8]
            : *(const short8*)&S[(mt * 16 + colL) * BP + (kb - 2) * 32 + kgrp * 8];
        #pragma unroll
        for (int nt = 0; nt < 4; ++nt) {
            short8 bw = *(const short8*)&W2T_l[(nt * 16 + colL) * 128 + kb * 32 + kgrp * 8];
            u[nt] = MFMA16(am, bw, u[nt], 0, 0, 0);
        }
    }

    // ---- residual + LayerNorm ----
    float y[4][4];
    float s1[4] = {0, 0, 0, 0}, s2[4] = {0, 0, 0, 0};
    #pragma unroll
    for (int j = 0; j < 4; ++j) {
        int node = nb0 + mt * 16 + kgrp * 4 + j;
        int nds  = (node < N_NODES) ? node : (N_NODES - 1);
        #pragma unroll
        for (int nt = 0; nt < 4; ++nt) {
            float v = feats[(size_t)nds * 64 + nt * 16 + colL] + u[nt][j];
            y[nt][j] = v;
            s1[j] += v; s2[j] += v * v;
        }
    }
    #pragma unroll
    for (int off = 1; off < 16; off <<= 1) {
        #pragma unroll
        for (int j = 0; j < 4; ++j) {
            s1[j] += __shfl_xor(s1[j], off, 64);
            s2[j] += __shfl_xor(s2[j], off, 64);
        }
    }
    float gv[4], bv[4];
    #pragma unroll
    for (int nt = 0; nt < 4; ++nt) {
        gv[nt] = ln_g_l[nt * 16 + colL];
        bv[nt] = ln_b_l[nt * 16 + colL];
    }
    #pragma unroll
    for (int j = 0; j < 4; ++j) {
        int node = nb0 + mt * 16 + kgrp * 4 + j;
        if (node >= N_NODES) continue;
        float mu  = s1[j] * (1.0f / 64.0f);
        float var = s2[j] * (1.0f / 64.0f) - mu * mu;
        float rr  = rsqrtf(var + 1e-5f);
        #pragma unroll
        for (int nt = 0; nt < 4; ++nt) {
            float o = (y[nt][j] - mu) * rr * gv[nt] + bv[nt];
            feats[(size_t)node * 64 + nt * 16 + colL]   = o;
            featsbf[(size_t)node * 64 + nt * 16 + colL] = (unsigned short)f2bf(o);
        }
    }
}

// ---------------- readout (MFMA, k_node template) ----------------

__global__ __launch_bounds__(256) void k_readout(const unsigned short* __restrict__ featsbf,
        const int* __restrict__ an,
        const unsigned short* __restrict__ Ro1T, const unsigned short* __restrict__ Ro2T,
        const float* __restrict__ ro_b1, const float* __restrict__ ro_b2,
        const float* __restrict__ ro_w3, const float* __restrict__ ro_b3,
        const float* __restrict__ atomic_e, float* __restrict__ blockpart) {
    __shared__ unsigned short P[64 * BP];   // feats
    __shared__ unsigned short Q[64 * BP];   // h1
    __shared__ float sred[256];
    const int tid  = threadIdx.x;
    const int lane = tid & 63;
    const int wib  = tid >> 6;
    const int mt   = __builtin_amdgcn_readfirstlane(wib);
    const int nb0  = blockIdx.x * 64;
    const int colL = lane & 15;
    const int kgrp = lane >> 4;

    #pragma unroll 4
    for (int i = 0; i < 16; ++i) {
        int r  = wib + i * 4;
        int nd = nb0 + r; nd = (nd < N_NODES) ? nd : (N_NODES - 1);
        P[r * BP + lane] = featsbf[(size_t)nd * 64 + lane];
    }
    __syncthreads();

    // ---- h1 = silu(x @ Ro1 + b1) ----
    {
        f32x4 m[4];
        #pragma unroll
        for (int nt = 0; nt < 4; ++nt) {
            float b = ro_b1[nt * 16 + colL];
            m[nt][0] = b; m[nt][1] = b; m[nt][2] = b; m[nt][3] = b;
        }
        #pragma unroll
        for (int kb = 0; kb < 2; ++kb) {
            short8 ax = *(const short8*)&P[(mt * 16 + colL) * BP + kb * 32 + kgrp * 8];
            #pragma unroll
            for (int nt = 0; nt < 4; ++nt) {
                short8 bw = *(const short8*)&Ro1T[(nt * 16 + colL) * 64 + kb * 32 + kgrp * 8];
                m[nt] = MFMA16(ax, bw, m[nt], 0, 0, 0);
            }
        }
        __syncthreads();
        #pragma unroll
        for (int nt = 0; nt < 4; ++nt)
            #pragma unroll
            for (int j = 0; j < 4; ++j)
                Q[(mt * 16 + kgrp * 4 + j) * BP + nt * 16 + colL] =
                    (unsigned short)f2bf(siluf(m[nt][j]));
    }
    __syncthreads();

    // ---- h2 = silu(h1 @ Ro2 + b2), 32 wide; e = h2 @ ro_w3 ----
    f32x4 u[2];
    #pragma unroll
    for (int nt = 0; nt < 2; ++nt) {
        float b = ro_b2[nt * 16 + colL];
        u[nt][0] = b; u[nt][1] = b; u[nt][2] = b; u[nt][3] = b;
    }
    #pragma unroll
    for (int kb = 0; kb < 2; ++kb) {
        short8 am = *(const short8*)&Q[(mt * 16 + colL) * BP + kb * 32 + kgrp * 8];
        #pragma unroll
        for (int nt = 0; nt < 2; ++nt) {
            short8 bw = *(const short8*)&Ro2T[(nt * 16 + colL) * 64 + kb * 32 + kgrp * 8];
            u[nt] = MFMA16(am, bw, u[nt], 0, 0, 0);
        }
    }
    float w3[2];
    #pragma unroll
    for (int nt = 0; nt < 2; ++nt) w3[nt] = ro_w3[nt * 16 + colL];
    float part = 0.0f;
    #pragma unroll
    for (int j = 0; j < 4; ++j) {
        float c = siluf(u[0][j]) * w3[0] + siluf(u[1][j]) * w3[1];
        #pragma unroll
        for (int off = 1; off < 16; off <<= 1) c += __shfl_xor(c, off, 64);
        int node = nb0 + mt * 16 + kgrp * 4 + j;
        if (colL == 0 && node < N_NODES)
            part += c + ro_b3[0] + atomic_e[an[node]];
    }
    sred[tid] = part;
    __syncthreads();
    for (int off = 128; off > 0; off >>= 1) {
        if (tid < off) sred[tid] += sred[tid + off];
        __syncthreads();
    }
    if (tid == 0) blockpart[blockIdx.x] = sred[0];
}

__global__ void k_final(const float* __restrict__ blockpart, int nb, float* __restrict__ out) {
    __shared__ float s[256];
    float acc = 0.f;
    for (int i = threadIdx.x; i < nb; i += 256) acc += blockpart[i];
    s[threadIdx.x] = acc; __syncthreads();
    for (int off = 128; off > 0; off >>= 1) {
        if (threadIdx.x < off) s[threadIdx.x] += s[threadIdx.x + off];
        __syncthreads();
    }
    if (threadIdx.x == 0) out[0] = s[0];
}

// ---------------- launch ----------------

extern "C" void kernel_launch(void* const* d_in, const int* in_sizes, int n_in,
                              void* d_out, int out_size, void* d_ws, size_t ws_size,
                              hipStream_t stream) {
    const int*   an       = (const int*)  d_in[0];
    const float* pos      = (const float*)d_in[1];
    const int*   edge     = (const int*)  d_in[2];
    const float* widths   = (const float*)d_in[3];
    const float* embed    = (const float*)d_in[4];
    const float* rad_w1   = (const float*)d_in[5];
    const float* rad_b1   = (const float*)d_in[6];
    const float* rad_w2   = (const float*)d_in[7];
    const float* rad_b2   = (const float*)d_in[8];
    const float* self_w   = (const float*)d_in[9];
    const float* self_b   = (const float*)d_in[10];
    const float* proj_w   = (const float*)d_in[11];
    const float* proj_b   = (const float*)d_in[12];
    const float* mlp_w1   = (const float*)d_in[13];
    const float* mlp_b1   = (const float*)d_in[14];
    const float* mlp_w2   = (const float*)d_in[15];
    const float* mlp_b2   = (const float*)d_in[16];
    const float* ln_g     = (const float*)d_in[17];
    const float* ln_b     = (const float*)d_in[18];
    const float* ro_w1    = (const float*)d_in[19];
    const float* ro_b1    = (const float*)d_in[20];
    const float* ro_w2    = (const float*)d_in[21];
    const float* ro_b2    = (const float*)d_in[22];
    const float* ro_w3    = (const float*)d_in[23];
    const float* ro_b3    = (const float*)d_in[24];
    const float* atomic_e = (const float*)d_in[25];

    char* w = (char*)d_ws;
    auto alloc = [&](size_t bytes) { char* p = w; w += (bytes + 255) & ~(size_t)255; return p; };
    float* feats     = (float*)alloc(sizeof(float) * N_NODES * HDIM);
    unsigned short* featsbf = (unsigned short*)alloc(sizeof(unsigned short) * N_NODES * HDIM);
    unsigned short* aggbf   = (unsigned short*)alloc(sizeof(unsigned short) * N_NODES * HDIM);
    unsigned short* lutB = (unsigned short*)alloc(sizeof(unsigned short) * NLAYER * TLUT * HDIM);
    float* W2s       = (float*)alloc(sizeof(float) * NLAYER * HDIM * HDIM);
    float* b2s       = (float*)alloc(sizeof(float) * NLAYER * HDIM);
    float* Wsp       = (float*)alloc(sizeof(float) * NLAYER * HDIM * HDIM);
    float* bsp       = (float*)alloc(sizeof(float) * NLAYER * HDIM);
    unsigned short* WspT = (unsigned short*)alloc(sizeof(unsigned short) * NLAYER * 4096);
    unsigned short* PbT  = (unsigned short*)alloc(sizeof(unsigned short) * NLAYER * 4096);
    unsigned short* W1T  = (unsigned short*)alloc(sizeof(unsigned short) * NLAYER * 8192);
    unsigned short* W2T  = (unsigned short*)alloc(sizeof(unsigned short) * NLAYER * 8192);
    unsigned short* Ro1T = (unsigned short*)alloc(sizeof(unsigned short) * 4096);
    unsigned short* Ro2T = (unsigned short*)alloc(sizeof(unsigned short) * 2048);
    unsigned int* erec = (unsigned int*)alloc(sizeof(unsigned int) * N_EDGES);
    unsigned int* binned = (unsigned int*)alloc(sizeof(unsigned int) * (size_t)NBKT * BCAP);
    int*   btail     = (int*)  alloc(sizeof(int) * 256);
    int*   bbase     = (int*)  alloc(sizeof(int) * 256);
    int*   starts    = (int*)  alloc(sizeof(int) * (N_NODES + 1));
    float* blockpart = (float*)alloc(sizeof(float) * 1024);
    (void)ws_size; (void)in_sizes; (void)n_in; (void)out_size;

    const int* erow = edge;
    const int* ecol = edge + N_EDGES;

    hipMemsetAsync(btail, 0, sizeof(int) * 256, stream);
    k_embed<<<12500, 256, 0, stream>>>(an, embed, feats, featsbf);
    k_binA<<<(N_EDGES + TILE - 1) / TILE, 256, 0, stream>>>(erow, ecol, pos, btail, binned);
    k_scanB<<<1, 256, 0, stream>>>(btail, bbase);
    k_binB<<<NBKT, 256, 0, stream>>>(binned, btail, bbase, starts, erec);
    k_prep<<<(NLAYER * HDIM * HDIM + NLAYER * HDIM + 255) / 256, 256, 0, stream>>>(
        rad_w2, self_w, proj_w, rad_b2, self_b, proj_b, W2s, Wsp, b2s, bsp);
    k_wtr<<<(NLAYER * 24576 + 6144 + 255) / 256, 256, 0, stream>>>(
        Wsp, proj_w, mlp_w1, mlp_w2, ro_w1, ro_w2, WspT, PbT, W1T, W2T, Ro1T, Ro2T);
    k_lut<<<NLAYER * TLUT, 64, 0, stream>>>(widths, rad_w1, rad_b1, W2s, b2s, lutB);

    for (int l = 0; l < NLAYER; ++l) {
        k_agg<<<12500, 256, 0, stream>>>((const uint4*)featsbf,
                                         (const uint4*)(lutB + (size_t)l * TLUT * HDIM),
                                         starts, erec, (uint4*)aggbf);
        k_node<<<782, 256, 0, stream>>>(feats, featsbf, aggbf,
            WspT + (size_t)l * 4096, PbT + (size_t)l * 4096,
            W1T + (size_t)l * 8192, W2T + (size_t)l * 8192,
            bsp + l * HDIM, mlp_b1 + l * 2 * HDIM, mlp_b2 + l * HDIM,
            ln_g + l * HDIM, ln_b + l * HDIM);
    }

    k_readout<<<782, 256, 0, stream>>>(featsbf, an, Ro1T, Ro2T, ro_b1, ro_b2,
                                       ro_w3, ro_b3, atomic_e, blockpart);
    k_final<<<1, 256, 0, stream>>>(blockpart, 782, (float*)d_out);
}

// Round 20
// 401.811 us; speedup vs baseline: 1.1144x; 1.0034x over previous
//
#include <hip/hip_runtime.h>
#include <hip/hip_fp16.h>
#include <math.h>

// Problem constants (from reference)
constexpr int N_NODES = 50000;
constexpr int N_EDGES = 1600000;
constexpr int HDIM    = 64;
constexpr int NLAYER  = 5;
constexpr int NBASIS  = 8;
constexpr int TLUT    = 256;           // radial LUT entries (8-bit index)
constexpr float CUT_R = 5.0f;
constexpr float PI_F  = 3.14159265358979f;

// binned scatter: buckets of 256 nodes (r >> 8)
constexpr int NBKT = 196;
constexpr int BCAP = 9216;             // mean 8192 + ~11 sigma
constexpr int TILE = 2048;

typedef __attribute__((ext_vector_type(8))) short short8;   // 8 bf16 (4 VGPRs)
typedef __attribute__((ext_vector_type(4))) float f32x4;    // MFMA acc
#define MFMA16 __builtin_amdgcn_mfma_f32_16x16x32_bf16

__device__ __forceinline__ float siluf(float x) { return x / (1.0f + __expf(-x)); }

// round-to-nearest-even f32 -> bf16 bits
__device__ __forceinline__ unsigned int f2bf(float x) {
    unsigned int b = __float_as_uint(x);
    return (b + 0x7fffu + ((b >> 16) & 1u)) >> 16;
}
__device__ __forceinline__ float bf_lo(unsigned int u) { return __uint_as_float(u << 16); }
__device__ __forceinline__ float bf_hi(unsigned int u) { return __uint_as_float(u & 0xffff0000u); }

// f32 -> fp8 e5m2 (RTNE via fp16 truncation with rounding)
__device__ __forceinline__ unsigned int f2e5(float x) {
    unsigned short b = __half_as_ushort(__float2half(x));
    return ((unsigned int)b + 0x7Fu + ((b >> 8) & 1u)) >> 8;
}
__device__ __forceinline__ float e5f(unsigned int u8) {
    return __half2float(__ushort_as_half((unsigned short)(u8 << 8)));
}

// block-wide exclusive scan of 256 values (one per thread): wave shuffle scans
// + 4-entry LDS combine; 2 barriers total.
__device__ __forceinline__ int blockScan256Excl(int cv, int tid, int* wtot) {
    int v = cv;
    int lane = tid & 63;
    #pragma unroll
    for (int off = 1; off < 64; off <<= 1) {
        int t = __shfl_up(v, off, 64);
        if (lane >= off) v += t;
    }
    if (lane == 63) wtot[tid >> 6] = v;
    __syncthreads();
    int pre = 0;
    #pragma unroll
    for (int w = 0; w < 4; ++w)
        if (w < (tid >> 6)) pre += wtot[w];
    __syncthreads();
    return v + pre - cv;                 // exclusive
}

// ---------------- setup kernels ----------------

__global__ void k_embed(const int* __restrict__ an, const float* __restrict__ embed,
                        float* __restrict__ feats, unsigned short* __restrict__ featsbf,
                        unsigned char* __restrict__ featsf8) {
    int i = blockIdx.x * blockDim.x + threadIdx.x;           // N*H threads
    if (i >= N_NODES * HDIM) return;
    int node = i >> 6, h = i & 63;
    float v = embed[an[node] * HDIM + h];
    feats[i] = v;
    featsbf[i] = (unsigned short)f2bf(v);
    featsf8[i] = (unsigned char)f2e5(v);
}

// pass A: block-sort TILE-edge tiles by node bucket (r>>8), append runs to binned[]
// rec packs (col<<16) | (nn<<8) | (r&255): 4 bytes total
__global__ __launch_bounds__(256) void k_binA(const int* __restrict__ row,
                                              const int* __restrict__ col,
                                              const float* __restrict__ pos,
                                              int* __restrict__ btail,
                                              unsigned int* __restrict__ binned) {
    __shared__ unsigned int ent[TILE];    // 8 KB
    __shared__ short bb[TILE];            // 4 KB
    __shared__ unsigned int sorted[TILE]; // 8 KB
    __shared__ short sortedB[TILE];       // 4 KB
    __shared__ int cnt[256], cnt2[256], base[256], gbase[256];
    __shared__ int wtot[4];
    const int tid = threadIdx.x;
    const int t0  = blockIdx.x * TILE;
    const int nv  = min(TILE, N_EDGES - t0);

    cnt[tid] = 0;
    __syncthreads();

    #pragma unroll
    for (int i = 0; i < TILE / 256; ++i) {
        int idx = i * 256 + tid;
        if (idx < nv) {
            int e = t0 + idx;
            int r = row[e], c = col[e];
            float dx = pos[c * 3 + 0] - pos[r * 3 + 0];
            float dy = pos[c * 3 + 1] - pos[r * 3 + 1];
            float dz = pos[c * 3 + 2] - pos[r * 3 + 2];
            float len = sqrtf(dx * dx + dy * dy + dz * dz);
            float t = len * ((float)(TLUT - 1) / CUT_R);
            t = fminf(t, (float)(TLUT - 1));
            unsigned int nn = (unsigned int)(t + 0.5f);
            if (nn > TLUT - 1) nn = TLUT - 1;
            ent[idx] = ((unsigned int)c << 16) | (nn << 8) | ((unsigned int)r & 255u);
            int b = r >> 8;
            bb[idx] = (short)b;
            atomicAdd(&cnt[b], 1);
        }
    }
    __syncthreads();
    int cv = cnt[tid];
    int excl = blockScan256Excl(cv, tid, wtot);
    base[tid] = excl;
    if (tid < NBKT && cv > 0) gbase[tid] = atomicAdd(&btail[tid], cv);
    cnt2[tid] = excl;
    __syncthreads();
    #pragma unroll
    for (int i = 0; i < TILE / 256; ++i) {
        int idx = i * 256 + tid;
        if (idx < nv) {
            int b = bb[idx];
            int p = atomicAdd(&cnt2[b], 1);
            sorted[p]  = ent[idx];
            sortedB[p] = (short)b;
        }
    }
    __syncthreads();
    for (int s = tid; s < nv; s += 256) {
        int b = sortedB[s];
        binned[(size_t)b * BCAP + gbase[b] + (s - base[b])] = sorted[s];
    }
}

// exclusive scan of 196 bucket totals (1 block, 256 threads)
__global__ void k_scanB(const int* __restrict__ btail, int* __restrict__ bbase) {
    __shared__ int wtot[4];
    int t = threadIdx.x;
    int v = (t < NBKT) ? btail[t] : 0;
    int excl = blockScan256Excl(v, t, wtot);
    if (t < NBKT) bbase[t] = excl;
}

// pass B: one block per 256-node bucket. LDS histogram -> wave scan -> starts ->
// scatter erec via LDS cursors. No global atomics.
__global__ __launch_bounds__(256) void k_binB(const unsigned int* __restrict__ binned,
                                              const int* __restrict__ btail,
                                              const int* __restrict__ bbase,
                                              int* __restrict__ starts,
                                              unsigned int* __restrict__ erec) {
    __shared__ int hist[256];
    __shared__ int cur[256];
    __shared__ int wtot[4];
    const int b = blockIdx.x;
    const int node0 = b << 8;
    const int t = threadIdx.x;
    hist[t] = 0;
    __syncthreads();
    const int cnt = btail[b];
    const unsigned int* src = binned + (size_t)b * BCAP;
    for (int s = t; s < cnt; s += 256)
        atomicAdd(&hist[src[s] & 255u], 1);
    __syncthreads();
    int h = hist[t];
    int excl = bbase[b] + blockScan256Excl(h, t, wtot);
    int n = node0 + t;
    if (n < N_NODES) starts[n] = excl;
    if (b == 0 && t == 0) starts[N_NODES] = N_EDGES;
    cur[t] = excl;
    __syncthreads();
    for (int s = t; s < cnt; s += 256) {
        unsigned int p = src[s];
        int pp = atomicAdd(&cur[p & 255u], 1);
        erec[pp] = p;
    }
}

// fused: W2s/Wsp (i < L*4096) + biases b2s/bsp (remainder)
__global__ void k_prep(const float* __restrict__ rad_w2, const float* __restrict__ self_w,
                       const float* __restrict__ proj_w,
                       const float* __restrict__ rad_b2, const float* __restrict__ self_b,
                       const float* __restrict__ proj_b,
                       float* __restrict__ W2s, float* __restrict__ Wsp,
                       float* __restrict__ b2s, float* __restrict__ bsp) {
    int i = blockIdx.x * blockDim.x + threadIdx.x;
    if (i < NLAYER * HDIM * HDIM) {
        int l = i / (HDIM * HDIM); int rem = i % (HDIM * HDIM);
        int k = rem / HDIM; int h = rem % HDIM;
        const float* w = rad_w2 + ((size_t)l * HDIM + k) * (HDIM * 3) + h * 3;
        W2s[i] = w[0] + w[1] + w[2];
        const float* sw = self_w + ((size_t)l * HDIM + k) * HDIM;
        const float* pw = proj_w + (size_t)l * 2 * HDIM * HDIM;
        float acc = 0.f;
        for (int m = 0; m < HDIM; ++m) acc += sw[m] * pw[m * HDIM + h];
        Wsp[i] = acc;
    } else {
        int i2 = i - NLAYER * HDIM * HDIM;
        if (i2 >= NLAYER * HDIM) return;
        int l = i2 / HDIM, h = i2 % HDIM;
        const float* rb2 = rad_b2 + l * HDIM * 3 + h * 3;
        b2s[i2] = rb2[0] + rb2[1] + rb2[2];
        float acc = proj_b[l * HDIM + h];
        const float* pw = proj_w + (size_t)l * 2 * HDIM * HDIM;
        const float* sb = self_b + l * HDIM;
        for (int m = 0; m < HDIM; ++m) acc += sb[m] * pw[m * HDIM + h];
        bsp[i2] = acc;
    }
}

// fused: bf16 transposed weights for MFMA B-operands + readout weights
__global__ void k_wtr(const float* __restrict__ Wsp, const float* __restrict__ proj_w,
                      const float* __restrict__ mlp_w1, const float* __restrict__ mlp_w2,
                      const float* __restrict__ ro_w1, const float* __restrict__ ro_w2,
                      unsigned short* __restrict__ WspT, unsigned short* __restrict__ PbT,
                      unsigned short* __restrict__ W1T, unsigned short* __restrict__ W2T,
                      unsigned short* __restrict__ Ro1T, unsigned short* __restrict__ Ro2T) {
    int i = blockIdx.x * blockDim.x + threadIdx.x;
    if (i < NLAYER * 24576) {
        int l = i / 24576, off = i % 24576;
        if (off < 4096) {
            int n = off >> 6, k = off & 63;
            WspT[(size_t)l * 4096 + off] = (unsigned short)f2bf(Wsp[(size_t)l * 4096 + k * 64 + n]);
        } else if (off < 8192) {
            int o = off - 4096; int n = o >> 6, k = o & 63;
            PbT[(size_t)l * 4096 + o] =
                (unsigned short)f2bf(proj_w[(size_t)l * 8192 + (64 + k) * 64 + n]);
        } else if (off < 16384) {
            int o = off - 8192; int n = o >> 6, k = o & 63;
            W1T[(size_t)l * 8192 + o] = (unsigned short)f2bf(mlp_w1[(size_t)l * 8192 + k * 128 + n]);
        } else {
            int o = off - 16384; int n = o >> 7, k = o & 127;
            W2T[(size_t)l * 8192 + o] = (unsigned short)f2bf(mlp_w2[(size_t)l * 8192 + k * 64 + n]);
        }
    } else {
        int i2 = i - NLAYER * 24576;
        if (i2 >= 6144) return;
        if (i2 < 4096) {
            int n = i2 >> 6, k = i2 & 63;
            Ro1T[i2] = (unsigned short)f2bf(ro_w1[k * 64 + n]);
        } else {
            int o = i2 - 4096; int n = o >> 6, k = o & 63;
            Ro2T[o] = (unsigned short)f2bf(ro_w2[k * 32 + n]);
        }
    }
}

// radial LUT -> bf16 directly
__global__ void k_lut(const float* __restrict__ widths, const float* __restrict__ rad_w1,
                      const float* __restrict__ rad_b1, const float* __restrict__ W2s,
                      const float* __restrict__ b2s, unsigned short* __restrict__ lutB) {
    int bid = blockIdx.x;                 // l*TLUT + t
    int l = bid / TLUT, t = bid % TLUT;
    int h = threadIdx.x;                  // 64 threads
    __shared__ float h1s[HDIM];
    float len = (float)t * (CUT_R / (float)(TLUT - 1));
    float cut = 0.0f;
    if (len < CUT_R) cut = 0.5f * (cosf(len * (PI_F / CUT_R)) + 1.0f);
    float acc = rad_b1[l * HDIM + h];
    for (int b = 0; b < NBASIS; ++b) {
        float wb = fmaxf(widths[b], 0.1f);
        float center = (float)b * (CUT_R / (float)(NBASIS - 1));
        float d = (len - center) / wb;
        float rbf = __expf(-0.5f * d * d) * cut;
        acc += rbf * rad_w1[(l * NBASIS + b) * HDIM + h];
    }
    h1s[h] = siluf(acc);
    __syncthreads();
    float o = b2s[l * HDIM + h];
    const float* w2 = W2s + (size_t)l * HDIM * HDIM;
    for (int k = 0; k < HDIM; ++k) o += h1s[k] * w2[k * HDIM + h];
    lutB[(size_t)bid * HDIM + h] = (unsigned short)f2bf(o);
}

// ---------------- per-layer kernels ----------------

// one wave per node, 8 edge slots x 8 lanes (8 channels each).
// feats gathered as fp8 e5m2 (3.2MB: fits per-XCD L2); LUT bf16 (L1-resident).
__global__ __launch_bounds__(256) void k_agg(const uint2* __restrict__ featsf8_2,
                                             const uint4* __restrict__ lutB4_l,
                                             const int* __restrict__ starts,
                                             const unsigned int* __restrict__ erec,
                                             uint4* __restrict__ aggbf4) {
    int wid  = (blockIdx.x * blockDim.x + threadIdx.x) >> 6;
    int lane = threadIdx.x & 63;
    int slot = lane >> 3;     // 0..7
    int j    = lane & 7;      // channel octet
    if (wid >= N_NODES) return;
    int e0 = starts[wid], e1 = starts[wid + 1];
    float a0 = 0, a1 = 0, a2 = 0, a3 = 0, a4 = 0, a5 = 0, a6 = 0, a7 = 0;
    #pragma unroll 2
    for (int e = e0 + slot; e < e1; e += 8) {
        unsigned int rec = erec[e];
        int c  = rec >> 16;
        int i0 = (rec >> 8) & 255;
        uint4 qw = lutB4_l[i0 * 8 + j];
        uint2 fb = featsf8_2[(size_t)c * 8 + j];      // 8 fp8 = channels 8j..8j+7
        a0 += e5f(fb.x & 255u)         * bf_lo(qw.x);
        a1 += e5f((fb.x >> 8) & 255u)  * bf_hi(qw.x);
        a2 += e5f((fb.x >> 16) & 255u) * bf_lo(qw.y);
        a3 += e5f(fb.x >> 24)          * bf_hi(qw.y);
        a4 += e5f(fb.y & 255u)         * bf_lo(qw.z);
        a5 += e5f((fb.y >> 8) & 255u)  * bf_hi(qw.z);
        a6 += e5f((fb.y >> 16) & 255u) * bf_lo(qw.w);
        a7 += e5f(fb.y >> 24)          * bf_hi(qw.w);
    }
    #pragma unroll
    for (int off = 8; off < 64; off <<= 1) {
        a0 += __shfl_xor(a0, off, 64);  a1 += __shfl_xor(a1, off, 64);
        a2 += __shfl_xor(a2, off, 64);  a3 += __shfl_xor(a3, off, 64);
        a4 += __shfl_xor(a4, off, 64);  a5 += __shfl_xor(a5, off, 64);
        a6 += __shfl_xor(a6, off, 64);  a7 += __shfl_xor(a7, off, 64);
    }
    if (slot == 0) {
        uint4 o;
        o.x = f2bf(a0) | (f2bf(a1) << 16);
        o.y = f2bf(a2) | (f2bf(a3) << 16);
        o.z = f2bf(a4) | (f2bf(a5) << 16);
        o.w = f2bf(a6) | (f2bf(a7) << 16);
        aggbf4[(size_t)wid * 8 + j] = o;
    }
}

// k_node v3 (MFMA): 64 nodes/block, 4 waves; wave w owns node rows [16w,16w+16).
constexpr int BP = 72;                     // bf16 LDS row pitch
__global__ __launch_bounds__(256) void k_node(float* __restrict__ feats,
        unsigned short* __restrict__ featsbf,
        unsigned char* __restrict__ featsf8,
        const unsigned short* __restrict__ aggbf,
        const unsigned short* __restrict__ WspT_l, const unsigned short* __restrict__ PbT_l,
        const unsigned short* __restrict__ W1T_l, const unsigned short* __restrict__ W2T_l,
        const float* __restrict__ bsp_l,
        const float* __restrict__ mlp_b1_l, const float* __restrict__ mlp_b2_l,
        const float* __restrict__ ln_g_l, const float* __restrict__ ln_b_l) {
    __shared__ unsigned short P[64 * BP];   // x -> conv
    __shared__ unsigned short Q[64 * BP];   // a -> m1_lo
    __shared__ unsigned short S[64 * BP];   // m1_hi
    const int tid  = threadIdx.x;
    const int lane = tid & 63;
    const int wib  = tid >> 6;
    const int mt   = __builtin_amdgcn_readfirstlane(wib);
    const int nb0  = blockIdx.x * 64;
    const int colL = lane & 15;
    const int kgrp = lane >> 4;

    #pragma unroll 4
    for (int i = 0; i < 16; ++i) {
        int r  = wib + i * 4;
        int nd = nb0 + r; nd = (nd < N_NODES) ? nd : (N_NODES - 1);
        P[r * BP + lane] = featsbf[(size_t)nd * 64 + lane];
        Q[r * BP + lane] = aggbf[(size_t)nd * 64 + lane];
    }
    __syncthreads();

    // ---- conv = x@Wsp + a@Pb + bsp ----
    f32x4 acc[4];
    #pragma unroll
    for (int nt = 0; nt < 4; ++nt) {
        float b = bsp_l[nt * 16 + colL];
        acc[nt][0] = b; acc[nt][1] = b; acc[nt][2] = b; acc[nt][3] = b;
    }
    #pragma unroll
    for (int kb = 0; kb < 2; ++kb) {
        short8 ax = *(const short8*)&P[(mt * 16 + colL) * BP + kb * 32 + kgrp * 8];
        short8 aa = *(const short8*)&Q[(mt * 16 + colL) * BP + kb * 32 + kgrp * 8];
        #pragma unroll
        for (int nt = 0; nt < 4; ++nt) {
            short8 bw = *(const short8*)&WspT_l[(nt * 16 + colL) * 64 + kb * 32 + kgrp * 8];
            acc[nt] = MFMA16(ax, bw, acc[nt], 0, 0, 0);
            short8 bp = *(const short8*)&PbT_l[(nt * 16 + colL) * 64 + kb * 32 + kgrp * 8];
            acc[nt] = MFMA16(aa, bp, acc[nt], 0, 0, 0);
        }
    }
    __syncthreads();
    #pragma unroll
    for (int nt = 0; nt < 4; ++nt)
        #pragma unroll
        for (int j = 0; j < 4; ++j)
            P[(mt * 16 + kgrp * 4 + j) * BP + nt * 16 + colL] = (unsigned short)f2bf(acc[nt][j]);
    __syncthreads();

    // ---- m1 = silu(conv@W1 + b1), 128 wide ----
    {
        f32x4 m[8];
        #pragma unroll
        for (int nt = 0; nt < 8; ++nt) {
            float b = mlp_b1_l[nt * 16 + colL];
            m[nt][0] = b; m[nt][1] = b; m[nt][2] = b; m[nt][3] = b;
        }
        #pragma unroll
        for (int kb = 0; kb < 2; ++kb) {
            short8 ac = *(const short8*)&P[(mt * 16 + colL) * BP + kb * 32 + kgrp * 8];
            #pragma unroll
            for (int nt = 0; nt < 8; ++nt) {
                short8 bw = *(const short8*)&W1T_l[(nt * 16 + colL) * 64 + kb * 32 + kgrp * 8];
                m[nt] = MFMA16(ac, bw, m[nt], 0, 0, 0);
            }
        }
        __syncthreads();
        #pragma unroll
        for (int nt = 0; nt < 4; ++nt)
            #pragma unroll
            for (int j = 0; j < 4; ++j)
                Q[(mt * 16 + kgrp * 4 + j) * BP + nt * 16 + colL] =
                    (unsigned short)f2bf(siluf(m[nt][j]));
        #pragma unroll
        for (int nt = 4; nt < 8; ++nt)
            #pragma unroll
            for (int j = 0; j < 4; ++j)
                S[(mt * 16 + kgrp * 4 + j) * BP + (nt - 4) * 16 + colL] =
                    (unsigned short)f2bf(siluf(m[nt][j]));
    }
    __syncthreads();

    // ---- upd = m1@W2 + b2 ----
    f32x4 u[4];
    #pragma unroll
    for (int nt = 0; nt < 4; ++nt) {
        float b = mlp_b2_l[nt * 16 + colL];
        u[nt][0] = b; u[nt][1] = b; u[nt][2] = b; u[nt][3] = b;
    }
    #pragma unroll
    for (int kb = 0; kb < 4; ++kb) {
        short8 am = (kb < 2)
            ? *(const short8*)&Q[(mt * 16 + colL) * BP + kb * 32 + kgrp * 8]
            : *(const short8*)&S[(mt * 16 + colL) * BP + (kb - 2) * 32 + kgrp * 8];
        #pragma unroll
        for (int nt = 0; nt < 4; ++nt) {
            short8 bw = *(const short8*)&W2T_l[(nt * 16 + colL) * 128 + kb * 32 + kgrp * 8];
            u[nt] = MFMA16(am, bw, u[nt], 0, 0, 0);
        }
    }

    // ---- residual + LayerNorm ----
    float y[4][4];
    float s1[4] = {0, 0, 0, 0}, s2[4] = {0, 0, 0, 0};
    #pragma unroll
    for (int j = 0; j < 4; ++j) {
        int node = nb0 + mt * 16 + kgrp * 4 + j;
        int nds  = (node < N_NODES) ? node : (N_NODES - 1);
        #pragma unroll
        for (int nt = 0; nt < 4; ++nt) {
            float v = feats[(size_t)nds * 64 + nt * 16 + colL] + u[nt][j];
            y[nt][j] = v;
            s1[j] += v; s2[j] += v * v;
        }
    }
    #pragma unroll
    for (int off = 1; off < 16; off <<= 1) {
        #pragma unroll
        for (int j = 0; j < 4; ++j) {
            s1[j] += __shfl_xor(s1[j], off, 64);
            s2[j] += __shfl_xor(s2[j], off, 64);
        }
    }
    float gv[4], bv[4];
    #pragma unroll
    for (int nt = 0; nt < 4; ++nt) {
        gv[nt] = ln_g_l[nt * 16 + colL];
        bv[nt] = ln_b_l[nt * 16 + colL];
    }
    #pragma unroll
    for (int j = 0; j < 4; ++j) {
        int node = nb0 + mt * 16 + kgrp * 4 + j;
        if (node >= N_NODES) continue;
        float mu  = s1[j] * (1.0f / 64.0f);
        float var = s2[j] * (1.0f / 64.0f) - mu * mu;
        float rr  = rsqrtf(var + 1e-5f);
        #pragma unroll
        for (int nt = 0; nt < 4; ++nt) {
            float o = (y[nt][j] - mu) * rr * gv[nt] + bv[nt];
            size_t idx = (size_t)node * 64 + nt * 16 + colL;
            feats[idx]   = o;
            featsbf[idx] = (unsigned short)f2bf(o);
            featsf8[idx] = (unsigned char)f2e5(o);
        }
    }
}

// ---------------- readout (MFMA, k_node template) ----------------

__global__ __launch_bounds__(256) void k_readout(const unsigned short* __restrict__ featsbf,
        const int* __restrict__ an,
        const unsigned short* __restrict__ Ro1T, const unsigned short* __restrict__ Ro2T,
        const float* __restrict__ ro_b1, const float* __restrict__ ro_b2,
        const float* __restrict__ ro_w3, const float* __restrict__ ro_b3,
        const float* __restrict__ atomic_e, float* __restrict__ blockpart) {
    __shared__ unsigned short P[64 * BP];   // feats
    __shared__ unsigned short Q[64 * BP];   // h1
    __shared__ float sred[256];
    const int tid  = threadIdx.x;
    const int lane = tid & 63;
    const int wib  = tid >> 6;
    const int mt   = __builtin_amdgcn_readfirstlane(wib);
    const int nb0  = blockIdx.x * 64;
    const int colL = lane & 15;
    const int kgrp = lane >> 4;

    #pragma unroll 4
    for (int i = 0; i < 16; ++i) {
        int r  = wib + i * 4;
        int nd = nb0 + r; nd = (nd < N_NODES) ? nd : (N_NODES - 1);
        P[r * BP + lane] = featsbf[(size_t)nd * 64 + lane];
    }
    __syncthreads();

    // ---- h1 = silu(x @ Ro1 + b1) ----
    {
        f32x4 m[4];
        #pragma unroll
        for (int nt = 0; nt < 4; ++nt) {
            float b = ro_b1[nt * 16 + colL];
            m[nt][0] = b; m[nt][1] = b; m[nt][2] = b; m[nt][3] = b;
        }
        #pragma unroll
        for (int kb = 0; kb < 2; ++kb) {
            short8 ax = *(const short8*)&P[(mt * 16 + colL) * BP + kb * 32 + kgrp * 8];
            #pragma unroll
            for (int nt = 0; nt < 4; ++nt) {
                short8 bw = *(const short8*)&Ro1T[(nt * 16 + colL) * 64 + kb * 32 + kgrp * 8];
                m[nt] = MFMA16(ax, bw, m[nt], 0, 0, 0);
            }
        }
        __syncthreads();
        #pragma unroll
        for (int nt = 0; nt < 4; ++nt)
            #pragma unroll
            for (int j = 0; j < 4; ++j)
                Q[(mt * 16 + kgrp * 4 + j) * BP + nt * 16 + colL] =
                    (unsigned short)f2bf(siluf(m[nt][j]));
    }
    __syncthreads();

    // ---- h2 = silu(h1 @ Ro2 + b2), 32 wide; e = h2 @ ro_w3 ----
    f32x4 u[2];
    #pragma unroll
    for (int nt = 0; nt < 2; ++nt) {
        float b = ro_b2[nt * 16 + colL];
        u[nt][0] = b; u[nt][1] = b; u[nt][2] = b; u[nt][3] = b;
    }
    #pragma unroll
    for (int kb = 0; kb < 2; ++kb) {
        short8 am = *(const short8*)&Q[(mt * 16 + colL) * BP + kb * 32 + kgrp * 8];
        #pragma unroll
        for (int nt = 0; nt < 2; ++nt) {
            short8 bw = *(const short8*)&Ro2T[(nt * 16 + colL) * 64 + kb * 32 + kgrp * 8];
            u[nt] = MFMA16(am, bw, u[nt], 0, 0, 0);
        }
    }
    float w3[2];
    #pragma unroll
    for (int nt = 0; nt < 2; ++nt) w3[nt] = ro_w3[nt * 16 + colL];
    float part = 0.0f;
    #pragma unroll
    for (int j = 0; j < 4; ++j) {
        float c = siluf(u[0][j]) * w3[0] + siluf(u[1][j]) * w3[1];
        #pragma unroll
        for (int off = 1; off < 16; off <<= 1) c += __shfl_xor(c, off, 64);
        int node = nb0 + mt * 16 + kgrp * 4 + j;
        if (colL == 0 && node < N_NODES)
            part += c + ro_b3[0] + atomic_e[an[node]];
    }
    sred[tid] = part;
    __syncthreads();
    for (int off = 128; off > 0; off >>= 1) {
        if (tid < off) sred[tid] += sred[tid + off];
        __syncthreads();
    }
    if (tid == 0) blockpart[blockIdx.x] = sred[0];
}

__global__ void k_final(const float* __restrict__ blockpart, int nb, float* __restrict__ out) {
    __shared__ float s[256];
    float acc = 0.f;
    for (int i = threadIdx.x; i < nb; i += 256) acc += blockpart[i];
    s[threadIdx.x] = acc; __syncthreads();
    for (int off = 128; off > 0; off >>= 1) {
        if (threadIdx.x < off) s[threadIdx.x] += s[threadIdx.x + off];
        __syncthreads();
    }
    if (threadIdx.x == 0) out[0] = s[0];
}

// ---------------- launch ----------------

extern "C" void kernel_launch(void* const* d_in, const int* in_sizes, int n_in,
                              void* d_out, int out_size, void* d_ws, size_t ws_size,
                              hipStream_t stream) {
    const int*   an       = (const int*)  d_in[0];
    const float* pos      = (const float*)d_in[1];
    const int*   edge     = (const int*)  d_in[2];
    const float* widths   = (const float*)d_in[3];
    const float* embed    = (const float*)d_in[4];
    const float* rad_w1   = (const float*)d_in[5];
    const float* rad_b1   = (const float*)d_in[6];
    const float* rad_w2   = (const float*)d_in[7];
    const float* rad_b2   = (const float*)d_in[8];
    const float* self_w   = (const float*)d_in[9];
    const float* self_b   = (const float*)d_in[10];
    const float* proj_w   = (const float*)d_in[11];
    const float* proj_b   = (const float*)d_in[12];
    const float* mlp_w1   = (const float*)d_in[13];
    const float* mlp_b1   = (const float*)d_in[14];
    const float* mlp_w2   = (const float*)d_in[15];
    const float* mlp_b2   = (const float*)d_in[16];
    const float* ln_g     = (const float*)d_in[17];
    const float* ln_b     = (const float*)d_in[18];
    const float* ro_w1    = (const float*)d_in[19];
    const float* ro_b1    = (const float*)d_in[20];
    const float* ro_w2    = (const float*)d_in[21];
    const float* ro_b2    = (const float*)d_in[22];
    const float* ro_w3    = (const float*)d_in[23];
    const float* ro_b3    = (const float*)d_in[24];
    const float* atomic_e = (const float*)d_in[25];

    char* w = (char*)d_ws;
    auto alloc = [&](size_t bytes) { char* p = w; w += (bytes + 255) & ~(size_t)255; return p; };
    float* feats     = (float*)alloc(sizeof(float) * N_NODES * HDIM);
    unsigned short* featsbf = (unsigned short*)alloc(sizeof(unsigned short) * N_NODES * HDIM);
    unsigned char* featsf8  = (unsigned char*)alloc(sizeof(unsigned char) * N_NODES * HDIM);
    unsigned short* aggbf   = (unsigned short*)alloc(sizeof(unsigned short) * N_NODES * HDIM);
    unsigned short* lutB = (unsigned short*)alloc(sizeof(unsigned short) * NLAYER * TLUT * HDIM);
    float* W2s       = (float*)alloc(sizeof(float) * NLAYER * HDIM * HDIM);
    float* b2s       = (float*)alloc(sizeof(float) * NLAYER * HDIM);
    float* Wsp       = (float*)alloc(sizeof(float) * NLAYER * HDIM * HDIM);
    float* bsp       = (float*)alloc(sizeof(float) * NLAYER * HDIM);
    unsigned short* WspT = (unsigned short*)alloc(sizeof(unsigned short) * NLAYER * 4096);
    unsigned short* PbT  = (unsigned short*)alloc(sizeof(unsigned short) * NLAYER * 4096);
    unsigned short* W1T  = (unsigned short*)alloc(sizeof(unsigned short) * NLAYER * 8192);
    unsigned short* W2T  = (unsigned short*)alloc(sizeof(unsigned short) * NLAYER * 8192);
    unsigned short* Ro1T = (unsigned short*)alloc(sizeof(unsigned short) * 4096);
    unsigned short* Ro2T = (unsigned short*)alloc(sizeof(unsigned short) * 2048);
    unsigned int* erec = (unsigned int*)alloc(sizeof(unsigned int) * N_EDGES);
    unsigned int* binned = (unsigned int*)alloc(sizeof(unsigned int) * (size_t)NBKT * BCAP);
    int*   btail     = (int*)  alloc(sizeof(int) * 256);
    int*   bbase     = (int*)  alloc(sizeof(int) * 256);
    int*   starts    = (int*)  alloc(sizeof(int) * (N_NODES + 1));
    float* blockpart = (float*)alloc(sizeof(float) * 1024);
    (void)ws_size; (void)in_sizes; (void)n_in; (void)out_size;

    const int* erow = edge;
    const int* ecol = edge + N_EDGES;

    hipMemsetAsync(btail, 0, sizeof(int) * 256, stream);
    k_embed<<<12500, 256, 0, stream>>>(an, embed, feats, featsbf, featsf8);
    k_binA<<<(N_EDGES + TILE - 1) / TILE, 256, 0, stream>>>(erow, ecol, pos, btail, binned);
    k_scanB<<<1, 256, 0, stream>>>(btail, bbase);
    k_binB<<<NBKT, 256, 0, stream>>>(binned, btail, bbase, starts, erec);
    k_prep<<<(NLAYER * HDIM * HDIM + NLAYER * HDIM + 255) / 256, 256, 0, stream>>>(
        rad_w2, self_w, proj_w, rad_b2, self_b, proj_b, W2s, Wsp, b2s, bsp);
    k_wtr<<<(NLAYER * 24576 + 6144 + 255) / 256, 256, 0, stream>>>(
        Wsp, proj_w, mlp_w1, mlp_w2, ro_w1, ro_w2, WspT, PbT, W1T, W2T, Ro1T, Ro2T);
    k_lut<<<NLAYER * TLUT, 64, 0, stream>>>(widths, rad_w1, rad_b1, W2s, b2s, lutB);

    for (int l = 0; l < NLAYER; ++l) {
        k_agg<<<12500, 256, 0, stream>>>((const uint2*)featsf8,
                                         (const uint4*)(lutB + (size_t)l * TLUT * HDIM),
                                         starts, erec, (uint4*)aggbf);
        k_node<<<782, 256, 0, stream>>>(feats, featsbf, featsf8, aggbf,
            WspT + (size_t)l * 4096, PbT + (size_t)l * 4096,
            W1T + (size_t)l * 8192, W2T + (size_t)l * 8192,
            bsp + l * HDIM, mlp_b1 + l * 2 * HDIM, mlp_b2 + l * HDIM,
            ln_g + l * HDIM, ln_b + l * HDIM);
    }

    k_readout<<<782, 256, 0, stream>>>(featsbf, an, Ro1T, Ro2T, ro_b1, ro_b2,
                                       ro_w3, ro_b3, atomic_e, blockpart);
    k_final<<<1, 256, 0, stream>>>(blockpart, 782, (float*)d_out);
}

// Round 21
// 395.856 us; speedup vs baseline: 1.1311x; 1.0150x over previous
//
#include <hip/hip_runtime.h>
#include <hip/hip_fp16.h>
#include <math.h>

// Problem constants (from reference)
constexpr int N_NODES = 50000;
constexpr int N_EDGES = 1600000;
constexpr int HDIM    = 64;
constexpr int NLAYER  = 5;
constexpr int NBASIS  = 8;
constexpr int TLUT    = 256;           // radial LUT entries (8-bit index)
constexpr float CUT_R = 5.0f;
constexpr float PI_F  = 3.14159265358979f;

// binned scatter: buckets of 256 nodes (r >> 8)
constexpr int NBKT = 196;
constexpr int BCAP = 9216;             // mean 8192 + ~11 sigma
constexpr int TILE = 2048;

typedef __attribute__((ext_vector_type(8))) short short8;   // 8 bf16 (4 VGPRs)
typedef __attribute__((ext_vector_type(4))) float f32x4;    // MFMA acc
#define MFMA16 __builtin_amdgcn_mfma_f32_16x16x32_bf16

__device__ __forceinline__ float siluf(float x) { return x / (1.0f + __expf(-x)); }

// round-to-nearest-even f32 -> bf16 bits
__device__ __forceinline__ unsigned int f2bf(float x) {
    unsigned int b = __float_as_uint(x);
    return (b + 0x7fffu + ((b >> 16) & 1u)) >> 16;
}
__device__ __forceinline__ float bf_lo(unsigned int u) { return __uint_as_float(u << 16); }
__device__ __forceinline__ float bf_hi(unsigned int u) { return __uint_as_float(u & 0xffff0000u); }

// f32 -> fp8 e5m2 (RTNE via fp16 truncation with rounding)
__device__ __forceinline__ unsigned int f2e5(float x) {
    unsigned short b = __half_as_ushort(__float2half(x));
    return ((unsigned int)b + 0x7Fu + ((b >> 8) & 1u)) >> 8;
}
__device__ __forceinline__ float e5f(unsigned int u8) {
    return __half2float(__ushort_as_half((unsigned short)(u8 << 8)));
}

// block-wide exclusive scan of 256 values: wave shuffle scans + LDS combine.
__device__ __forceinline__ int blockScan256Excl(int cv, int tid, int* wtot) {
    int v = cv;
    int lane = tid & 63;
    #pragma unroll
    for (int off = 1; off < 64; off <<= 1) {
        int t = __shfl_up(v, off, 64);
        if (lane >= off) v += t;
    }
    if (lane == 63) wtot[tid >> 6] = v;
    __syncthreads();
    int pre = 0;
    #pragma unroll
    for (int w = 0; w < 4; ++w)
        if (w < (tid >> 6)) pre += wtot[w];
    __syncthreads();
    return v + pre - cv;                 // exclusive
}

// ---------------- setup kernels ----------------

__global__ void k_embed(const int* __restrict__ an, const float* __restrict__ embed,
                        unsigned short* __restrict__ featsbf,
                        unsigned char* __restrict__ featsf8) {
    int i = blockIdx.x * blockDim.x + threadIdx.x;           // N*H threads
    if (i >= N_NODES * HDIM) return;
    int node = i >> 6, h = i & 63;
    float v = embed[an[node] * HDIM + h];
    featsbf[i] = (unsigned short)f2bf(v);
    featsf8[i] = (unsigned char)f2e5(v);
}

// per-edge record precompute (coalesced, no LDS -> full occupancy hides gathers)
// rec packs (col<<16) | (nn<<8) | (r&255); bkt = r>>8
__global__ void k_edge(const int* __restrict__ row, const int* __restrict__ col,
                       const float* __restrict__ pos,
                       unsigned int* __restrict__ rec4, unsigned char* __restrict__ bkt) {
    int e = blockIdx.x * blockDim.x + threadIdx.x;
    if (e >= N_EDGES) return;
    int r = row[e], c = col[e];
    float dx = pos[c * 3 + 0] - pos[r * 3 + 0];
    float dy = pos[c * 3 + 1] - pos[r * 3 + 1];
    float dz = pos[c * 3 + 2] - pos[r * 3 + 2];
    float len = sqrtf(dx * dx + dy * dy + dz * dz);
    float t = len * ((float)(TLUT - 1) / CUT_R);
    t = fminf(t, (float)(TLUT - 1));
    unsigned int nn = (unsigned int)(t + 0.5f);
    if (nn > TLUT - 1) nn = TLUT - 1;
    rec4[e] = ((unsigned int)c << 16) | (nn << 8) | ((unsigned int)r & 255u);
    bkt[e]  = (unsigned char)(r >> 8);
}

// pass A v2: pure LDS sort of precomputed records into bucket runs
__global__ __launch_bounds__(256) void k_binA(const unsigned int* __restrict__ rec4,
                                              const unsigned char* __restrict__ bkt,
                                              int* __restrict__ btail,
                                              unsigned int* __restrict__ binned) {
    __shared__ unsigned int ent[TILE];    // 8 KB
    __shared__ short bb[TILE];            // 4 KB
    __shared__ unsigned int sorted[TILE]; // 8 KB
    __shared__ short sortedB[TILE];       // 4 KB
    __shared__ int cnt[256], cnt2[256], base[256], gbase[256];
    __shared__ int wtot[4];
    const int tid = threadIdx.x;
    const int t0  = blockIdx.x * TILE;
    const int nv  = min(TILE, N_EDGES - t0);

    cnt[tid] = 0;
    __syncthreads();

    #pragma unroll
    for (int i = 0; i < TILE / 256; ++i) {
        int idx = i * 256 + tid;
        if (idx < nv) {
            ent[idx] = rec4[t0 + idx];
            int b = bkt[t0 + idx];
            bb[idx] = (short)b;
            atomicAdd(&cnt[b], 1);
        }
    }
    __syncthreads();
    int cv = cnt[tid];
    int excl = blockScan256Excl(cv, tid, wtot);
    base[tid] = excl;
    if (tid < NBKT && cv > 0) gbase[tid] = atomicAdd(&btail[tid], cv);
    cnt2[tid] = excl;
    __syncthreads();
    #pragma unroll
    for (int i = 0; i < TILE / 256; ++i) {
        int idx = i * 256 + tid;
        if (idx < nv) {
            int b = bb[idx];
            int p = atomicAdd(&cnt2[b], 1);
            sorted[p]  = ent[idx];
            sortedB[p] = (short)b;
        }
    }
    __syncthreads();
    for (int s = tid; s < nv; s += 256) {
        int b = sortedB[s];
        binned[(size_t)b * BCAP + gbase[b] + (s - base[b])] = sorted[s];
    }
}

// exclusive scan of 196 bucket totals (1 block, 256 threads)
__global__ void k_scanB(const int* __restrict__ btail, int* __restrict__ bbase) {
    __shared__ int wtot[4];
    int t = threadIdx.x;
    int v = (t < NBKT) ? btail[t] : 0;
    int excl = blockScan256Excl(v, t, wtot);
    if (t < NBKT) bbase[t] = excl;
}

// pass B: one block per 256-node bucket. LDS histogram -> wave scan -> starts ->
// scatter erec via LDS cursors. No global atomics.
__global__ __launch_bounds__(256) void k_binB(const unsigned int* __restrict__ binned,
                                              const int* __restrict__ btail,
                                              const int* __restrict__ bbase,
                                              int* __restrict__ starts,
                                              unsigned int* __restrict__ erec) {
    __shared__ int hist[256];
    __shared__ int cur[256];
    __shared__ int wtot[4];
    const int b = blockIdx.x;
    const int node0 = b << 8;
    const int t = threadIdx.x;
    hist[t] = 0;
    __syncthreads();
    const int cnt = btail[b];
    const unsigned int* src = binned + (size_t)b * BCAP;
    for (int s = t; s < cnt; s += 256)
        atomicAdd(&hist[src[s] & 255u], 1);
    __syncthreads();
    int h = hist[t];
    int excl = bbase[b] + blockScan256Excl(h, t, wtot);
    int n = node0 + t;
    if (n < N_NODES) starts[n] = excl;
    if (b == 0 && t == 0) starts[N_NODES] = N_EDGES;
    cur[t] = excl;
    __syncthreads();
    for (int s = t; s < cnt; s += 256) {
        unsigned int p = src[s];
        int pp = atomicAdd(&cur[p & 255u], 1);
        erec[pp] = p;
    }
}

// fused: W2s/Wsp (i < L*4096) + biases b2s/bsp (remainder)
__global__ void k_prep(const float* __restrict__ rad_w2, const float* __restrict__ self_w,
                       const float* __restrict__ proj_w,
                       const float* __restrict__ rad_b2, const float* __restrict__ self_b,
                       const float* __restrict__ proj_b,
                       float* __restrict__ W2s, float* __restrict__ Wsp,
                       float* __restrict__ b2s, float* __restrict__ bsp) {
    int i = blockIdx.x * blockDim.x + threadIdx.x;
    if (i < NLAYER * HDIM * HDIM) {
        int l = i / (HDIM * HDIM); int rem = i % (HDIM * HDIM);
        int k = rem / HDIM; int h = rem % HDIM;
        const float* w = rad_w2 + ((size_t)l * HDIM + k) * (HDIM * 3) + h * 3;
        W2s[i] = w[0] + w[1] + w[2];
        const float* sw = self_w + ((size_t)l * HDIM + k) * HDIM;
        const float* pw = proj_w + (size_t)l * 2 * HDIM * HDIM;
        float acc = 0.f;
        for (int m = 0; m < HDIM; ++m) acc += sw[m] * pw[m * HDIM + h];
        Wsp[i] = acc;
    } else {
        int i2 = i - NLAYER * HDIM * HDIM;
        if (i2 >= NLAYER * HDIM) return;
        int l = i2 / HDIM, h = i2 % HDIM;
        const float* rb2 = rad_b2 + l * HDIM * 3 + h * 3;
        b2s[i2] = rb2[0] + rb2[1] + rb2[2];
        float acc = proj_b[l * HDIM + h];
        const float* pw = proj_w + (size_t)l * 2 * HDIM * HDIM;
        const float* sb = self_b + l * HDIM;
        for (int m = 0; m < HDIM; ++m) acc += sb[m] * pw[m * HDIM + h];
        bsp[i2] = acc;
    }
}

// fused: bf16 transposed weights for MFMA B-operands + readout weights
__global__ void k_wtr(const float* __restrict__ Wsp, const float* __restrict__ proj_w,
                      const float* __restrict__ mlp_w1, const float* __restrict__ mlp_w2,
                      const float* __restrict__ ro_w1, const float* __restrict__ ro_w2,
                      unsigned short* __restrict__ WspT, unsigned short* __restrict__ PbT,
                      unsigned short* __restrict__ W1T, unsigned short* __restrict__ W2T,
                      unsigned short* __restrict__ Ro1T, unsigned short* __restrict__ Ro2T) {
    int i = blockIdx.x * blockDim.x + threadIdx.x;
    if (i < NLAYER * 24576) {
        int l = i / 24576, off = i % 24576;
        if (off < 4096) {
            int n = off >> 6, k = off & 63;
            WspT[(size_t)l * 4096 + off] = (unsigned short)f2bf(Wsp[(size_t)l * 4096 + k * 64 + n]);
        } else if (off < 8192) {
            int o = off - 4096; int n = o >> 6, k = o & 63;
            PbT[(size_t)l * 4096 + o] =
                (unsigned short)f2bf(proj_w[(size_t)l * 8192 + (64 + k) * 64 + n]);
        } else if (off < 16384) {
            int o = off - 8192; int n = o >> 6, k = o & 63;
            W1T[(size_t)l * 8192 + o] = (unsigned short)f2bf(mlp_w1[(size_t)l * 8192 + k * 128 + n]);
        } else {
            int o = off - 16384; int n = o >> 7, k = o & 127;
            W2T[(size_t)l * 8192 + o] = (unsigned short)f2bf(mlp_w2[(size_t)l * 8192 + k * 64 + n]);
        }
    } else {
        int i2 = i - NLAYER * 24576;
        if (i2 >= 6144) return;
        if (i2 < 4096) {
            int n = i2 >> 6, k = i2 & 63;
            Ro1T[i2] = (unsigned short)f2bf(ro_w1[k * 64 + n]);
        } else {
            int o = i2 - 4096; int n = o >> 6, k = o & 63;
            Ro2T[o] = (unsigned short)f2bf(ro_w2[k * 32 + n]);
        }
    }
}

// radial LUT -> bf16 directly
__global__ void k_lut(const float* __restrict__ widths, const float* __restrict__ rad_w1,
                      const float* __restrict__ rad_b1, const float* __restrict__ W2s,
                      const float* __restrict__ b2s, unsigned short* __restrict__ lutB) {
    int bid = blockIdx.x;                 // l*TLUT + t
    int l = bid / TLUT, t = bid % TLUT;
    int h = threadIdx.x;                  // 64 threads
    __shared__ float h1s[HDIM];
    float len = (float)t * (CUT_R / (float)(TLUT - 1));
    float cut = 0.0f;
    if (len < CUT_R) cut = 0.5f * (cosf(len * (PI_F / CUT_R)) + 1.0f);
    float acc = rad_b1[l * HDIM + h];
    for (int b = 0; b < NBASIS; ++b) {
        float wb = fmaxf(widths[b], 0.1f);
        float center = (float)b * (CUT_R / (float)(NBASIS - 1));
        float d = (len - center) / wb;
        float rbf = __expf(-0.5f * d * d) * cut;
        acc += rbf * rad_w1[(l * NBASIS + b) * HDIM + h];
    }
    h1s[h] = siluf(acc);
    __syncthreads();
    float o = b2s[l * HDIM + h];
    const float* w2 = W2s + (size_t)l * HDIM * HDIM;
    for (int k = 0; k < HDIM; ++k) o += h1s[k] * w2[k * HDIM + h];
    lutB[(size_t)bid * HDIM + h] = (unsigned short)f2bf(o);
}

// ---------------- per-layer kernels ----------------

// one wave per node, 8 edge slots x 8 lanes (8 channels each).
// feats gathered as fp8 e5m2 (3.2MB); LUT bf16 (L1-resident).
__global__ __launch_bounds__(256) void k_agg(const uint2* __restrict__ featsf8_2,
                                             const uint4* __restrict__ lutB4_l,
                                             const int* __restrict__ starts,
                                             const unsigned int* __restrict__ erec,
                                             uint4* __restrict__ aggbf4) {
    int wid  = (blockIdx.x * blockDim.x + threadIdx.x) >> 6;
    int lane = threadIdx.x & 63;
    int slot = lane >> 3;     // 0..7
    int j    = lane & 7;      // channel octet
    if (wid >= N_NODES) return;
    int e0 = starts[wid], e1 = starts[wid + 1];
    float a0 = 0, a1 = 0, a2 = 0, a3 = 0, a4 = 0, a5 = 0, a6 = 0, a7 = 0;
    #pragma unroll 2
    for (int e = e0 + slot; e < e1; e += 8) {
        unsigned int rec = erec[e];
        int c  = rec >> 16;
        int i0 = (rec >> 8) & 255;
        uint4 qw = lutB4_l[i0 * 8 + j];
        uint2 fb = featsf8_2[(size_t)c * 8 + j];      // 8 fp8 = channels 8j..8j+7
        a0 += e5f(fb.x & 255u)         * bf_lo(qw.x);
        a1 += e5f((fb.x >> 8) & 255u)  * bf_hi(qw.x);
        a2 += e5f((fb.x >> 16) & 255u) * bf_lo(qw.y);
        a3 += e5f(fb.x >> 24)          * bf_hi(qw.y);
        a4 += e5f(fb.y & 255u)         * bf_lo(qw.z);
        a5 += e5f((fb.y >> 8) & 255u)  * bf_hi(qw.z);
        a6 += e5f((fb.y >> 16) & 255u) * bf_lo(qw.w);
        a7 += e5f(fb.y >> 24)          * bf_hi(qw.w);
    }
    #pragma unroll
    for (int off = 8; off < 64; off <<= 1) {
        a0 += __shfl_xor(a0, off, 64);  a1 += __shfl_xor(a1, off, 64);
        a2 += __shfl_xor(a2, off, 64);  a3 += __shfl_xor(a3, off, 64);
        a4 += __shfl_xor(a4, off, 64);  a5 += __shfl_xor(a5, off, 64);
        a6 += __shfl_xor(a6, off, 64);  a7 += __shfl_xor(a7, off, 64);
    }
    if (slot == 0) {
        uint4 o;
        o.x = f2bf(a0) | (f2bf(a1) << 16);
        o.y = f2bf(a2) | (f2bf(a3) << 16);
        o.z = f2bf(a4) | (f2bf(a5) << 16);
        o.w = f2bf(a6) | (f2bf(a7) << 16);
        aggbf4[(size_t)wid * 8 + j] = o;
    }
}

// k_node v4 (MFMA): 64 nodes/block, 4 waves. Residual taken from the LDS bf16
// copy of feats (no f32 master array).
constexpr int BP = 72;                     // bf16 LDS row pitch
__global__ __launch_bounds__(256) void k_node(
        unsigned short* __restrict__ featsbf,
        unsigned char* __restrict__ featsf8,
        const unsigned short* __restrict__ aggbf,
        const unsigned short* __restrict__ WspT_l, const unsigned short* __restrict__ PbT_l,
        const unsigned short* __restrict__ W1T_l, const unsigned short* __restrict__ W2T_l,
        const float* __restrict__ bsp_l,
        const float* __restrict__ mlp_b1_l, const float* __restrict__ mlp_b2_l,
        const float* __restrict__ ln_g_l, const float* __restrict__ ln_b_l) {
    __shared__ unsigned short P[64 * BP];   // x -> conv
    __shared__ unsigned short Q[64 * BP];   // a -> m1_lo
    __shared__ unsigned short S[64 * BP];   // m1_hi
    const int tid  = threadIdx.x;
    const int lane = tid & 63;
    const int wib  = tid >> 6;
    const int mt   = __builtin_amdgcn_readfirstlane(wib);
    const int nb0  = blockIdx.x * 64;
    const int colL = lane & 15;
    const int kgrp = lane >> 4;

    #pragma unroll 4
    for (int i = 0; i < 16; ++i) {
        int r  = wib + i * 4;
        int nd = nb0 + r; nd = (nd < N_NODES) ? nd : (N_NODES - 1);
        P[r * BP + lane] = featsbf[(size_t)nd * 64 + lane];
        Q[r * BP + lane] = aggbf[(size_t)nd * 64 + lane];
    }
    __syncthreads();

    // snapshot residual x (bf16 from LDS) before P is overwritten by conv
    float xres[4][4];                       // [nt][j]
    #pragma unroll
    for (int j = 0; j < 4; ++j)
        #pragma unroll
        for (int nt = 0; nt < 4; ++nt)
            xres[nt][j] = bf_lo(P[(mt * 16 + kgrp * 4 + j) * BP + nt * 16 + colL]);

    // ---- conv = x@Wsp + a@Pb + bsp ----
    f32x4 acc[4];
    #pragma unroll
    for (int nt = 0; nt < 4; ++nt) {
        float b = bsp_l[nt * 16 + colL];
        acc[nt][0] = b; acc[nt][1] = b; acc[nt][2] = b; acc[nt][3] = b;
    }
    #pragma unroll
    for (int kb = 0; kb < 2; ++kb) {
        short8 ax = *(const short8*)&P[(mt * 16 + colL) * BP + kb * 32 + kgrp * 8];
        short8 aa = *(const short8*)&Q[(mt * 16 + colL) * BP + kb * 32 + kgrp * 8];
        #pragma unroll
        for (int nt = 0; nt < 4; ++nt) {
            short8 bw = *(const short8*)&WspT_l[(nt * 16 + colL) * 64 + kb * 32 + kgrp * 8];
            acc[nt] = MFMA16(ax, bw, acc[nt], 0, 0, 0);
            short8 bp = *(const short8*)&PbT_l[(nt * 16 + colL) * 64 + kb * 32 + kgrp * 8];
            acc[nt] = MFMA16(aa, bp, acc[nt], 0, 0, 0);
        }
    }
    __syncthreads();
    #pragma unroll
    for (int nt = 0; nt < 4; ++nt)
        #pragma unroll
        for (int j = 0; j < 4; ++j)
            P[(mt * 16 + kgrp * 4 + j) * BP + nt * 16 + colL] = (unsigned short)f2bf(acc[nt][j]);
    __syncthreads();

    // ---- m1 = silu(conv@W1 + b1), 128 wide ----
    {
        f32x4 m[8];
        #pragma unroll
        for (int nt = 0; nt < 8; ++nt) {
            float b = mlp_b1_l[nt * 16 + colL];
            m[nt][0] = b; m[nt][1] = b; m[nt][2] = b; m[nt][3] = b;
        }
        #pragma unroll
        for (int kb = 0; kb < 2; ++kb) {
            short8 ac = *(const short8*)&P[(mt * 16 + colL) * BP + kb * 32 + kgrp * 8];
            #pragma unroll
            for (int nt = 0; nt < 8; ++nt) {
                short8 bw = *(const short8*)&W1T_l[(nt * 16 + colL) * 64 + kb * 32 + kgrp * 8];
                m[nt] = MFMA16(ac, bw, m[nt], 0, 0, 0);
            }
        }
        __syncthreads();
        #pragma unroll
        for (int nt = 0; nt < 4; ++nt)
            #pragma unroll
            for (int j = 0; j < 4; ++j)
                Q[(mt * 16 + kgrp * 4 + j) * BP + nt * 16 + colL] =
                    (unsigned short)f2bf(siluf(m[nt][j]));
        #pragma unroll
        for (int nt = 4; nt < 8; ++nt)
            #pragma unroll
            for (int j = 0; j < 4; ++j)
                S[(mt * 16 + kgrp * 4 + j) * BP + (nt - 4) * 16 + colL] =
                    (unsigned short)f2bf(siluf(m[nt][j]));
    }
    __syncthreads();

    // ---- upd = m1@W2 + b2 ----
    f32x4 u[4];
    #pragma unroll
    for (int nt = 0; nt < 4; ++nt) {
        float b = mlp_b2_l[nt * 16 + colL];
        u[nt][0] = b; u[nt][1] = b; u[nt][2] = b; u[nt][3] = b;
    }
    #pragma unroll
    for (int kb = 0; kb < 4; ++kb) {
        short8 am = (kb < 2)
            ? *(const short8*)&Q[(mt * 16 + colL) * BP + kb * 32 + kgrp * 8]
            : *(const short8*)&S[(mt * 16 + colL) * BP + (kb - 2) * 32 + kgrp * 8];
        #pragma unroll
        for (int nt = 0; nt < 4; ++nt) {
            short8 bw = *(const short8*)&W2T_l[(nt * 16 + colL) * 128 + kb * 32 + kgrp * 8];
            u[nt] = MFMA16(am, bw, u[nt], 0, 0, 0);
        }
    }

    // ---- residual (from LDS snapshot) + LayerNorm ----
    float y[4][4];
    float s1[4] = {0, 0, 0, 0}, s2[4] = {0, 0, 0, 0};
    #pragma unroll
    for (int j = 0; j < 4; ++j) {
        #pragma unroll
        for (int nt = 0; nt < 4; ++nt) {
            float v = xres[nt][j] + u[nt][j];
            y[nt][j] = v;
            s1[j] += v; s2[j] += v * v;
        }
    }
    #pragma unroll
    for (int off = 1; off < 16; off <<= 1) {
        #pragma unroll
        for (int j = 0; j < 4; ++j) {
            s1[j] += __shfl_xor(s1[j], off, 64);
            s2[j] += __shfl_xor(s2[j], off, 64);
        }
    }
    float gv[4], bv[4];
    #pragma unroll
    for (int nt = 0; nt < 4; ++nt) {
        gv[nt] = ln_g_l[nt * 16 + colL];
        bv[nt] = ln_b_l[nt * 16 + colL];
    }
    #pragma unroll
    for (int j = 0; j < 4; ++j) {
        int node = nb0 + mt * 16 + kgrp * 4 + j;
        if (node >= N_NODES) continue;
        float mu  = s1[j] * (1.0f / 64.0f);
        float var = s2[j] * (1.0f / 64.0f) - mu * mu;
        float rr  = rsqrtf(var + 1e-5f);
        #pragma unroll
        for (int nt = 0; nt < 4; ++nt) {
            float o = (y[nt][j] - mu) * rr * gv[nt] + bv[nt];
            size_t idx = (size_t)node * 64 + nt * 16 + colL;
            featsbf[idx] = (unsigned short)f2bf(o);
            featsf8[idx] = (unsigned char)f2e5(o);
        }
    }
}

// ---------------- readout (MFMA, k_node template) ----------------

__global__ __launch_bounds__(256) void k_readout(const unsigned short* __restrict__ featsbf,
        const int* __restrict__ an,
        const unsigned short* __restrict__ Ro1T, const unsigned short* __restrict__ Ro2T,
        const float* __restrict__ ro_b1, const float* __restrict__ ro_b2,
        const float* __restrict__ ro_w3, const float* __restrict__ ro_b3,
        const float* __restrict__ atomic_e, float* __restrict__ blockpart) {
    __shared__ unsigned short P[64 * BP];   // feats
    __shared__ unsigned short Q[64 * BP];   // h1
    __shared__ float sred[256];
    const int tid  = threadIdx.x;
    const int lane = tid & 63;
    const int wib  = tid >> 6;
    const int mt   = __builtin_amdgcn_readfirstlane(wib);
    const int nb0  = blockIdx.x * 64;
    const int colL = lane & 15;
    const int kgrp = lane >> 4;

    #pragma unroll 4
    for (int i = 0; i < 16; ++i) {
        int r  = wib + i * 4;
        int nd = nb0 + r; nd = (nd < N_NODES) ? nd : (N_NODES - 1);
        P[r * BP + lane] = featsbf[(size_t)nd * 64 + lane];
    }
    __syncthreads();

    // ---- h1 = silu(x @ Ro1 + b1) ----
    {
        f32x4 m[4];
        #pragma unroll
        for (int nt = 0; nt < 4; ++nt) {
            float b = ro_b1[nt * 16 + colL];
            m[nt][0] = b; m[nt][1] = b; m[nt][2] = b; m[nt][3] = b;
        }
        #pragma unroll
        for (int kb = 0; kb < 2; ++kb) {
            short8 ax = *(const short8*)&P[(mt * 16 + colL) * BP + kb * 32 + kgrp * 8];
            #pragma unroll
            for (int nt = 0; nt < 4; ++nt) {
                short8 bw = *(const short8*)&Ro1T[(nt * 16 + colL) * 64 + kb * 32 + kgrp * 8];
                m[nt] = MFMA16(ax, bw, m[nt], 0, 0, 0);
            }
        }
        __syncthreads();
        #pragma unroll
        for (int nt = 0; nt < 4; ++nt)
            #pragma unroll
            for (int j = 0; j < 4; ++j)
                Q[(mt * 16 + kgrp * 4 + j) * BP + nt * 16 + colL] =
                    (unsigned short)f2bf(siluf(m[nt][j]));
    }
    __syncthreads();

    // ---- h2 = silu(h1 @ Ro2 + b2), 32 wide; e = h2 @ ro_w3 ----
    f32x4 u[2];
    #pragma unroll
    for (int nt = 0; nt < 2; ++nt) {
        float b = ro_b2[nt * 16 + colL];
        u[nt][0] = b; u[nt][1] = b; u[nt][2] = b; u[nt][3] = b;
    }
    #pragma unroll
    for (int kb = 0; kb < 2; ++kb) {
        short8 am = *(const short8*)&Q[(mt * 16 + colL) * BP + kb * 32 + kgrp * 8];
        #pragma unroll
        for (int nt = 0; nt < 2; ++nt) {
            short8 bw = *(const short8*)&Ro2T[(nt * 16 + colL) * 64 + kb * 32 + kgrp * 8];
            u[nt] = MFMA16(am, bw, u[nt], 0, 0, 0);
        }
    }
    float w3[2];
    #pragma unroll
    for (int nt = 0; nt < 2; ++nt) w3[nt] = ro_w3[nt * 16 + colL];
    float part = 0.0f;
    #pragma unroll
    for (int j = 0; j < 4; ++j) {
        float c = siluf(u[0][j]) * w3[0] + siluf(u[1][j]) * w3[1];
        #pragma unroll
        for (int off = 1; off < 16; off <<= 1) c += __shfl_xor(c, off, 64);
        int node = nb0 + mt * 16 + kgrp * 4 + j;
        if (colL == 0 && node < N_NODES)
            part += c + ro_b3[0] + atomic_e[an[node]];
    }
    sred[tid] = part;
    __syncthreads();
    for (int off = 128; off > 0; off >>= 1) {
        if (tid < off) sred[tid] += sred[tid + off];
        __syncthreads();
    }
    if (tid == 0) blockpart[blockIdx.x] = sred[0];
}

__global__ void k_final(const float* __restrict__ blockpart, int nb, float* __restrict__ out) {
    __shared__ float s[256];
    float acc = 0.f;
    for (int i = threadIdx.x; i < nb; i += 256) acc += blockpart[i];
    s[threadIdx.x] = acc; __syncthreads();
    for (int off = 128; off > 0; off >>= 1) {
        if (threadIdx.x < off) s[threadIdx.x] += s[threadIdx.x + off];
        __syncthreads();
    }
    if (threadIdx.x == 0) out[0] = s[0];
}

// ---------------- launch ----------------

extern "C" void kernel_launch(void* const* d_in, const int* in_sizes, int n_in,
                              void* d_out, int out_size, void* d_ws, size_t ws_size,
                              hipStream_t stream) {
    const int*   an       = (const int*)  d_in[0];
    const float* pos      = (const float*)d_in[1];
    const int*   edge     = (const int*)  d_in[2];
    const float* widths   = (const float*)d_in[3];
    const float* embed    = (const float*)d_in[4];
    const float* rad_w1   = (const float*)d_in[5];
    const float* rad_b1   = (const float*)d_in[6];
    const float* rad_w2   = (const float*)d_in[7];
    const float* rad_b2   = (const float*)d_in[8];
    const float* self_w   = (const float*)d_in[9];
    const float* self_b   = (const float*)d_in[10];
    const float* proj_w   = (const float*)d_in[11];
    const float* proj_b   = (const float*)d_in[12];
    const float* mlp_w1   = (const float*)d_in[13];
    const float* mlp_b1   = (const float*)d_in[14];
    const float* mlp_w2   = (const float*)d_in[15];
    const float* mlp_b2   = (const float*)d_in[16];
    const float* ln_g     = (const float*)d_in[17];
    const float* ln_b     = (const float*)d_in[18];
    const float* ro_w1    = (const float*)d_in[19];
    const float* ro_b1    = (const float*)d_in[20];
    const float* ro_w2    = (const float*)d_in[21];
    const float* ro_b2    = (const float*)d_in[22];
    const float* ro_w3    = (const float*)d_in[23];
    const float* ro_b3    = (const float*)d_in[24];
    const float* atomic_e = (const float*)d_in[25];

    char* w = (char*)d_ws;
    auto alloc = [&](size_t bytes) { char* p = w; w += (bytes + 255) & ~(size_t)255; return p; };
    unsigned short* featsbf = (unsigned short*)alloc(sizeof(unsigned short) * N_NODES * HDIM);
    unsigned char* featsf8  = (unsigned char*)alloc(sizeof(unsigned char) * N_NODES * HDIM);
    unsigned short* aggbf   = (unsigned short*)alloc(sizeof(unsigned short) * N_NODES * HDIM);
    unsigned short* lutB = (unsigned short*)alloc(sizeof(unsigned short) * NLAYER * TLUT * HDIM);
    float* W2s       = (float*)alloc(sizeof(float) * NLAYER * HDIM * HDIM);
    float* b2s       = (float*)alloc(sizeof(float) * NLAYER * HDIM);
    float* Wsp       = (float*)alloc(sizeof(float) * NLAYER * HDIM * HDIM);
    float* bsp       = (float*)alloc(sizeof(float) * NLAYER * HDIM);
    unsigned short* WspT = (unsigned short*)alloc(sizeof(unsigned short) * NLAYER * 4096);
    unsigned short* PbT  = (unsigned short*)alloc(sizeof(unsigned short) * NLAYER * 4096);
    unsigned short* W1T  = (unsigned short*)alloc(sizeof(unsigned short) * NLAYER * 8192);
    unsigned short* W2T  = (unsigned short*)alloc(sizeof(unsigned short) * NLAYER * 8192);
    unsigned short* Ro1T = (unsigned short*)alloc(sizeof(unsigned short) * 4096);
    unsigned short* Ro2T = (unsigned short*)alloc(sizeof(unsigned short) * 2048);
    unsigned int* erec = (unsigned int*)alloc(sizeof(unsigned int) * N_EDGES);
    unsigned int* rec4 = (unsigned int*)alloc(sizeof(unsigned int) * N_EDGES);
    unsigned char* bkt = (unsigned char*)alloc(sizeof(unsigned char) * N_EDGES);
    unsigned int* binned = (unsigned int*)alloc(sizeof(unsigned int) * (size_t)NBKT * BCAP);
    int*   btail     = (int*)  alloc(sizeof(int) * 256);
    int*   bbase     = (int*)  alloc(sizeof(int) * 256);
    int*   starts    = (int*)  alloc(sizeof(int) * (N_NODES + 1));
    float* blockpart = (float*)alloc(sizeof(float) * 1024);
    (void)ws_size; (void)in_sizes; (void)n_in; (void)out_size;

    const int* erow = edge;
    const int* ecol = edge + N_EDGES;

    hipMemsetAsync(btail, 0, sizeof(int) * 256, stream);
    k_embed<<<12500, 256, 0, stream>>>(an, embed, featsbf, featsf8);
    k_edge<<<(N_EDGES + 255) / 256, 256, 0, stream>>>(erow, ecol, pos, rec4, bkt);
    k_binA<<<(N_EDGES + TILE - 1) / TILE, 256, 0, stream>>>(rec4, bkt, btail, binned);
    k_scanB<<<1, 256, 0, stream>>>(btail, bbase);
    k_binB<<<NBKT, 256, 0, stream>>>(binned, btail, bbase, starts, erec);
    k_prep<<<(NLAYER * HDIM * HDIM + NLAYER * HDIM + 255) / 256, 256, 0, stream>>>(
        rad_w2, self_w, proj_w, rad_b2, self_b, proj_b, W2s, Wsp, b2s, bsp);
    k_wtr<<<(NLAYER * 24576 + 6144 + 255) / 256, 256, 0, stream>>>(
        Wsp, proj_w, mlp_w1, mlp_w2, ro_w1, ro_w2, WspT, PbT, W1T, W2T, Ro1T, Ro2T);
    k_lut<<<NLAYER * TLUT, 64, 0, stream>>>(widths, rad_w1, rad_b1, W2s, b2s, lutB);

    for (int l = 0; l < NLAYER; ++l) {
        k_agg<<<12500, 256, 0, stream>>>((const uint2*)featsf8,
                                         (const uint4*)(lutB + (size_t)l * TLUT * HDIM),
                                         starts, erec, (uint4*)aggbf);
        k_node<<<782, 256, 0, stream>>>(featsbf, featsf8, aggbf,
            WspT + (size_t)l * 4096, PbT + (size_t)l * 4096,
            W1T + (size_t)l * 8192, W2T + (size_t)l * 8192,
            bsp + l * HDIM, mlp_b1 + l * 2 * HDIM, mlp_b2 + l * HDIM,
            ln_g + l * HDIM, ln_b + l * HDIM);
    }

    k_readout<<<782, 256, 0, stream>>>(featsbf, an, Ro1T, Ro2T, ro_b1, ro_b2,
                                       ro_w3, ro_b3, atomic_e, blockpart);
    k_final<<<1, 256, 0, stream>>>(blockpart, 782, (float*)d_out);
}